// Round 12
// baseline (876.106 us; speedup 1.0000x reference)
//
#include <hip/hip_runtime.h>
#include <hip/hip_bf16.h>
#include <math.h>

#define DI __device__ __forceinline__

typedef __attribute__((ext_vector_type(8))) short bf16x8;
typedef __attribute__((ext_vector_type(4))) short bf16x4;
typedef __attribute__((ext_vector_type(8))) _Float16 f16x8;
typedef __attribute__((ext_vector_type(4))) _Float16 f16x4;
typedef __attribute__((ext_vector_type(4))) float f32x4;

DI float b2f(short s) {
    unsigned u = ((unsigned)(unsigned short)s) << 16;
    return __builtin_bit_cast(float, u);
}
DI short f2b(float f) {
    unsigned u = __builtin_bit_cast(unsigned, f);
    unsigned r = (u + 0x7fffu + ((u >> 16) & 1u)) >> 16;
    return (short)(unsigned short)r;
}
struct hl16 { _Float16 h, l; };
DI hl16 fsp(float f) {
    hl16 r;
    r.h = (_Float16)f;
    r.l = (_Float16)((f - (float)r.h) * 2048.0f);
    return r;
}

// ---------------------------------------------------------------- rmsnorm
template <int MODE>
__global__ __launch_bounds__(256) void rmsnorm_k(const float* __restrict__ x,
                                                 const float* __restrict__ w,
                                                 void* __restrict__ o1,
                                                 void* __restrict__ o2) {
    int row = blockIdx.x, tid = threadIdx.x;
    const float* xr = x + (long)row * 2048;
    float4 a = *(const float4*)(xr + tid * 8);
    float4 b = *(const float4*)(xr + tid * 8 + 4);
    float ss = a.x * a.x + a.y * a.y + a.z * a.z + a.w * a.w +
               b.x * b.x + b.y * b.y + b.z * b.z + b.w * b.w;
    for (int m = 1; m < 64; m <<= 1) ss += __shfl_xor(ss, m);
    __shared__ float red[4];
    if ((tid & 63) == 0) red[tid >> 6] = ss;
    __syncthreads();
    float sc = rsqrtf((red[0] + red[1] + red[2] + red[3]) * (1.0f / 2048.0f) + 1e-6f);
    float4 wa = *(const float4*)(w + tid * 8);
    float4 wb = *(const float4*)(w + tid * 8 + 4);
    float v[8] = {a.x * sc * wa.x, a.y * sc * wa.y, a.z * sc * wa.z, a.w * sc * wa.w,
                  b.x * sc * wb.x, b.y * sc * wb.y, b.z * sc * wb.z, b.w * sc * wb.w};
    if (MODE == 0) {
        f16x8 h, l;
        for (int j = 0; j < 8; ++j) { hl16 t = fsp(v[j]); h[j] = t.h; l[j] = t.l; }
        *(f16x8*)((_Float16*)o1 + (long)row * 2048 + tid * 8) = h;
        *(f16x8*)((_Float16*)o2 + (long)row * 2048 + tid * 8) = l;
    } else {
        bf16x8 o;
        for (int j = 0; j < 8; ++j) o[j] = f2b(v[j]);
        *(bf16x8*)((short*)o1 + (long)row * 2048 + tid * 8) = o;
    }
}

// ---------------------------------------------------------------- transpose + split: f32 [R][C] -> planes [C][R]
__global__ __launch_bounds__(256) void tsplit_k(const float* __restrict__ in, int ldin,
                                                _Float16* __restrict__ outh,
                                                _Float16* __restrict__ outl, int ldout) {
    __shared__ float t[64][68];
    int r0 = blockIdx.x * 64, c0 = blockIdx.y * 64;
    int tid = threadIdx.x;
    int rr = tid >> 2, cs = (tid & 3) * 16;
    const float* src = in + (long)(r0 + rr) * ldin + c0 + cs;
    for (int u = 0; u < 4; ++u) {
        float4 v = *(const float4*)(src + u * 4);
        t[rr][cs + u * 4 + 0] = v.x; t[rr][cs + u * 4 + 1] = v.y;
        t[rr][cs + u * 4 + 2] = v.z; t[rr][cs + u * 4 + 3] = v.w;
    }
    __syncthreads();
    int cr = tid >> 2, rs = (tid & 3) * 16;
    f16x8 h0, l0, h1, l1;
    for (int u = 0; u < 8; ++u)  { hl16 e = fsp(t[rs + u][cr]);     h0[u] = e.h; l0[u] = e.l; }
    for (int u = 0; u < 8; ++u)  { hl16 e = fsp(t[rs + 8 + u][cr]); h1[u] = e.h; l1[u] = e.l; }
    long ob = (long)(c0 + cr) * ldout + r0 + rs;
    *(f16x8*)(outh + ob) = h0; *(f16x8*)(outh + ob + 8) = h1;
    *(f16x8*)(outl + ob) = l0; *(f16x8*)(outl + ob + 8) = l1;
}

// ---------------------------------------------------------------- weight prep: f32 [E][R][C] -> bf16 [E][C][R]
__global__ __launch_bounds__(256) void wprep_k(const float* __restrict__ in,
                                               short* __restrict__ outp,
                                               int R, int C) {
    __shared__ float t[64][68];
    int r0 = blockIdx.x * 64, c0 = blockIdx.y * 64;
    long es = (long)R * C;
    in += blockIdx.z * es;
    outp += blockIdx.z * es;
    int tid = threadIdx.x;
    int rr = tid >> 2, cs = (tid & 3) * 16;
    const float* src = in + (long)(r0 + rr) * C + c0 + cs;
    for (int u = 0; u < 4; ++u) {
        float4 v = *(const float4*)(src + u * 4);
        t[rr][cs + u * 4 + 0] = v.x; t[rr][cs + u * 4 + 1] = v.y;
        t[rr][cs + u * 4 + 2] = v.z; t[rr][cs + u * 4 + 3] = v.w;
    }
    __syncthreads();
    int cr = tid >> 2, rs = (tid & 3) * 16;
    bf16x8 o0, o1;
    for (int u = 0; u < 8; ++u) o0[u] = f2b(t[rs + u][cr]);
    for (int u = 0; u < 8; ++u) o1[u] = f2b(t[rs + 8 + u][cr]);
    long ob = (long)(c0 + cr) * R + r0 + rs;
    *(bf16x8*)(outp + ob) = o0;
    *(bf16x8*)(outp + ob + 8) = o1;
}

// ---------------------------------------------------------------- precise GEMM on planes
// BM=128, BN=64, BK=64. 4 waves as 2Mx2N, wave tile 64x32.
enum { EPI_F32 = 0, EPI_RESID = 1 };

template <int EPI>
__global__ __launch_bounds__(256) void pgemm_k(
    const _Float16* __restrict__ Ah, const _Float16* __restrict__ Al, int lda,
    const _Float16* __restrict__ Bh, const _Float16* __restrict__ Bl, int ldb,
    float* __restrict__ C, int ldc,
    const float* __restrict__ resid, int K) {
    __shared__ __align__(16) _Float16 sAh[128][68], sAl[128][68];
    __shared__ __align__(16) _Float16 sBh[64][68], sBl[64][68];
    int n0 = blockIdx.x * 64, m0 = blockIdx.y * 128;
    int tid = threadIdx.x, lane = tid & 63, wv = tid >> 6;
    int wm = (wv >> 1) * 64, wn = (wv & 1) * 32;
    int ln = lane & 15, g8 = (lane >> 4) * 8, rg = lane >> 4;
    int tr = tid >> 3, tc = (tid & 7) * 8;

    f32x4 a1[4][2], a2[4][2];
    for (int i = 0; i < 4; ++i)
        for (int j = 0; j < 2; ++j) { a1[i][j] = f32x4{0,0,0,0}; a2[i][j] = f32x4{0,0,0,0}; }

    for (int k0 = 0; k0 < K; k0 += 64) {
        for (int s = 0; s < 4; ++s) {
            int r = tr + s * 32;
            long ga = (long)(m0 + r) * lda + k0 + tc;
            *(f16x8*)&sAh[r][tc] = *(const f16x8*)(Ah + ga);
            *(f16x8*)&sAl[r][tc] = *(const f16x8*)(Al + ga);
        }
        for (int s = 0; s < 2; ++s) {
            int r = tr + s * 32;
            long gb = (long)(n0 + r) * ldb + k0 + tc;
            *(f16x8*)&sBh[r][tc] = *(const f16x8*)(Bh + gb);
            *(f16x8*)&sBl[r][tc] = *(const f16x8*)(Bl + gb);
        }
        __syncthreads();
        for (int kk = 0; kk < 2; ++kk) {
            f16x8 ah[4], alo[4], bh[2], blo[2];
            for (int i = 0; i < 4; ++i) {
                int r = wm + i * 16 + ln;
                ah[i]  = *(const f16x8*)&sAh[r][kk * 32 + g8];
                alo[i] = *(const f16x8*)&sAl[r][kk * 32 + g8];
            }
            for (int j = 0; j < 2; ++j) {
                int r = wn + j * 16 + ln;
                bh[j]  = *(const f16x8*)&sBh[r][kk * 32 + g8];
                blo[j] = *(const f16x8*)&sBl[r][kk * 32 + g8];
            }
            for (int i = 0; i < 4; ++i)
                for (int j = 0; j < 2; ++j) {
                    a1[i][j] = __builtin_amdgcn_mfma_f32_16x16x32_f16(ah[i], bh[j], a1[i][j], 0, 0, 0);
                    a2[i][j] = __builtin_amdgcn_mfma_f32_16x16x32_f16(alo[i], bh[j], a2[i][j], 0, 0, 0);
                    a2[i][j] = __builtin_amdgcn_mfma_f32_16x16x32_f16(ah[i], blo[j], a2[i][j], 0, 0, 0);
                }
        }
        __syncthreads();
    }
    for (int i = 0; i < 4; ++i)
        for (int r = 0; r < 4; ++r) {
            int m = m0 + wm + i * 16 + rg * 4 + r;
            for (int j = 0; j < 2; ++j) {
                int col = n0 + wn + j * 16 + ln;
                float v = a1[i][j][r] + a2[i][j][r] * (1.0f / 2048.0f);
                if (EPI == EPI_RESID) v += resid[(long)m * ldc + col];
                C[(long)m * ldc + col] = v;
            }
        }
}

// ---------------------------------------------------------------- bf16 GEMM (down-proj path)
enum { MEPI_BF16 = 0, MEPI_ATOMIC = 1 };

template <int EPI, bool EXPERT>
__global__ __launch_bounds__(256) void bgemm_k(
    const short* __restrict__ A, int lda,
    const short* __restrict__ Bt, int ldb, long bStride,
    void* __restrict__ C, int ldc,
    const int* __restrict__ perm, const float* __restrict__ permw,
    const int* __restrict__ offsets,
    int K, int gatherA, int gatherC) {
    __shared__ __align__(16) short sA[128][72], sB[128][72];

    int n0 = blockIdx.x * 128;
    int base = 0, cnt = 1 << 30, m0;
    if (EXPERT) {
        int e = blockIdx.y >> 4;
        m0 = (blockIdx.y & 15) * 128;
        base = offsets[e];
        cnt = offsets[e + 1] - base;
        if (m0 >= cnt) return;
        Bt += (long)e * bStride;
    } else {
        m0 = blockIdx.y * 128;
    }

    int tid = threadIdx.x, lane = tid & 63, wv = tid >> 6;
    int wm = (wv >> 1) * 64, wn = (wv & 1) * 64;
    int ln = lane & 15, g8 = (lane >> 4) * 8, rg = lane >> 4;
    int tr = tid >> 3, tc = (tid & 7) * 8;

    const short* aRow[4];
    for (int s = 0; s < 4; ++s) {
        int m = m0 + tr + s * 32;
        if (EXPERT && m >= cnt) m = cnt - 1;
        int arow;
        if (EXPERT) arow = gatherA ? perm[base + m] : (base + m);
        else arow = m;
        aRow[s] = A + (long)arow * lda;
    }

    f32x4 acc[4][4];
    for (int i = 0; i < 4; ++i)
        for (int j = 0; j < 4; ++j) acc[i][j] = f32x4{0.f, 0.f, 0.f, 0.f};

    for (int k0 = 0; k0 < K; k0 += 64) {
        for (int s = 0; s < 4; ++s) {
            int r = tr + s * 32;
            *(bf16x8*)&sA[r][tc] = *(const bf16x8*)(aRow[s] + k0 + tc);
            *(bf16x8*)&sB[r][tc] = *(const bf16x8*)(Bt + (long)(n0 + r) * ldb + k0 + tc);
        }
        __syncthreads();
        for (int kk = 0; kk < 2; ++kk) {
            bf16x8 af[4], bfr[4];
            for (int i = 0; i < 4; ++i)
                af[i] = *(const bf16x8*)&sA[wm + i * 16 + ln][kk * 32 + g8];
            for (int j = 0; j < 4; ++j)
                bfr[j] = *(const bf16x8*)&sB[wn + j * 16 + ln][kk * 32 + g8];
            for (int i = 0; i < 4; ++i)
                for (int j = 0; j < 4; ++j)
                    acc[i][j] = __builtin_amdgcn_mfma_f32_16x16x32_bf16(af[i], bfr[j], acc[i][j], 0, 0, 0);
        }
        __syncthreads();
    }

    for (int i = 0; i < 4; ++i) {
        for (int r = 0; r < 4; ++r) {
            int m = m0 + wm + i * 16 + rg * 4 + r;
            if (EXPERT && m >= cnt) continue;
            int crow;
            if (EXPERT) crow = gatherC ? perm[base + m] : (base + m);
            else crow = m;
            float cs = 1.0f;
            if (EPI == MEPI_ATOMIC && EXPERT && gatherC) cs = permw[base + m];
            for (int j = 0; j < 4; ++j) {
                int col = n0 + wn + j * 16 + ln;
                float v = acc[i][j][r];
                if (EPI == MEPI_BF16)
                    ((short*)C)[(long)crow * ldc + col] = f2b(v);
                else
                    atomicAdd(&((float*)C)[(long)crow * ldc + col], v * cs);
            }
        }
    }
}

// ---------------------------------------------------------------- fused gate/up GEMM + SiLU
// act[row][n0..n0+63] = silu(g)*u. B staging: sB rows [0,64) = g rows (n0+r),
// rows [64,128) = u rows (1024+n0+r-64). 2Mx2N waves: wave = 64 rows x 32 cols (g AND u).
template <bool EXPERT>
__global__ __launch_bounds__(256) void gugemm_k(
    const short* __restrict__ A, int lda,
    const short* __restrict__ Bt, int ldb, long bStride,
    short* __restrict__ act,
    const int* __restrict__ perm, const int* __restrict__ offsets, int K) {
    __shared__ __align__(16) short sA[128][72], sB[128][72];

    int n0 = blockIdx.x * 64;
    int base = 0, cnt = 1 << 30, m0;
    if (EXPERT) {
        int e = blockIdx.y >> 4;
        m0 = (blockIdx.y & 15) * 128;
        base = offsets[e];
        cnt = offsets[e + 1] - base;
        if (m0 >= cnt) return;
        Bt += (long)e * bStride;
    } else {
        m0 = blockIdx.y * 128;
    }

    int tid = threadIdx.x, lane = tid & 63, wv = tid >> 6;
    int wm = (wv >> 1) * 64, wn = (wv & 1) * 32;
    int ln = lane & 15, g8 = (lane >> 4) * 8, rg = lane >> 4;
    int tr = tid >> 3, tc = (tid & 7) * 8;

    const short* aRow[4];
    for (int s = 0; s < 4; ++s) {
        int m = m0 + tr + s * 32;
        if (EXPERT && m >= cnt) m = cnt - 1;
        int arow;
        if (EXPERT) arow = perm[base + m];
        else arow = m;
        aRow[s] = A + (long)arow * lda;
    }
    long bRow[4];
    for (int s = 0; s < 4; ++s) {
        int r = tr + s * 32;
        int gr = (r < 64) ? (n0 + r) : (1024 + n0 + r - 64);
        bRow[s] = (long)gr * ldb;
    }

    f32x4 accg[4][2], accu[4][2];
    for (int i = 0; i < 4; ++i)
        for (int j = 0; j < 2; ++j) { accg[i][j] = f32x4{0.f,0.f,0.f,0.f}; accu[i][j] = f32x4{0.f,0.f,0.f,0.f}; }

    for (int k0 = 0; k0 < K; k0 += 64) {
        for (int s = 0; s < 4; ++s) {
            int r = tr + s * 32;
            *(bf16x8*)&sA[r][tc] = *(const bf16x8*)(aRow[s] + k0 + tc);
            *(bf16x8*)&sB[r][tc] = *(const bf16x8*)(Bt + bRow[s] + k0 + tc);
        }
        __syncthreads();
        for (int kk = 0; kk < 2; ++kk) {
            bf16x8 af[4], bg[2], bu[2];
            for (int i = 0; i < 4; ++i)
                af[i] = *(const bf16x8*)&sA[wm + i * 16 + ln][kk * 32 + g8];
            for (int j = 0; j < 2; ++j) {
                bg[j] = *(const bf16x8*)&sB[wn + j * 16 + ln][kk * 32 + g8];
                bu[j] = *(const bf16x8*)&sB[64 + wn + j * 16 + ln][kk * 32 + g8];
            }
            for (int i = 0; i < 4; ++i)
                for (int j = 0; j < 2; ++j) {
                    accg[i][j] = __builtin_amdgcn_mfma_f32_16x16x32_bf16(af[i], bg[j], accg[i][j], 0, 0, 0);
                    accu[i][j] = __builtin_amdgcn_mfma_f32_16x16x32_bf16(af[i], bu[j], accu[i][j], 0, 0, 0);
                }
        }
        __syncthreads();
    }

    for (int i = 0; i < 4; ++i) {
        for (int r = 0; r < 4; ++r) {
            int m = m0 + wm + i * 16 + rg * 4 + r;
            if (EXPERT && m >= cnt) continue;
            int crow = EXPERT ? (base + m) : m;
            for (int j = 0; j < 2; ++j) {
                int col = n0 + wn + j * 16 + ln;
                // replicate old gu->silu chain bitwise: f2b, b2f, silu, f2b
                float gf = b2f(f2b(accg[i][j][r]));
                float uf = b2f(f2b(accu[i][j][r]));
                float s = gf / (1.0f + __expf(-gf));
                act[(long)crow * 1024 + col] = f2b(s * uf);
            }
        }
    }
}

// ---------------------------------------------------------------- rope table (f64 accurate)
__global__ __launch_bounds__(64) void ropetab_k(const int* __restrict__ pos,
                                                float* __restrict__ tab) {
    int s = blockIdx.x, d = threadIdx.x;
    double inv = pow(10000.0, -(double)d / 64.0);
    double fr = (double)pos[s] * inv;
    tab[s * 128 + d] = (float)cos(fr);
    tab[s * 128 + 64 + d] = (float)sin(fr);
}

// rope q in-place; rope k -> split planes
__global__ __launch_bounds__(256) void ropeall_k(float* __restrict__ qkvf,
                                                 const float* __restrict__ tab,
                                                 _Float16* __restrict__ kh,
                                                 _Float16* __restrict__ kl) {
    int s = blockIdx.x, sub = threadIdx.x >> 6, d = threadIdx.x & 63;
    int hh = blockIdx.y * 4 + sub;
    float c = tab[s * 128 + d], sn = tab[s * 128 + 64 + d];
    if (hh < 16) {
        float* row = qkvf + (long)s * 3072 + hh * 128;
        float x1 = row[d], x2 = row[d + 64];
        row[d] = x1 * c - x2 * sn;
        row[d + 64] = x1 * sn + x2 * c;
    } else {
        int kvh = hh - 16;
        const float* row = qkvf + (long)s * 3072 + 2048 + kvh * 128;
        float x1 = row[d], x2 = row[d + 64];
        float y1 = x1 * c - x2 * sn, y2 = x1 * sn + x2 * c;
        hl16 a = fsp(y1), b = fsp(y2);
        long base = ((long)kvh * 2048 + s) * 128;
        kh[base + d] = a.h; kl[base + d] = a.l;
        kh[base + 64 + d] = b.h; kl[base + 64 + d] = b.l;
    }
}

// V transpose + split: qkvf v-section -> vt planes [kvh][128][2048]
__global__ __launch_bounds__(256) void vprep_k(const float* __restrict__ qkvf,
                                               _Float16* __restrict__ vth,
                                               _Float16* __restrict__ vtl) {
    __shared__ float t[64][68];
    int s0 = blockIdx.x * 64, d0 = blockIdx.y * 64, kvh = blockIdx.z;
    int tid = threadIdx.x;
    int rr = tid >> 2, cs = (tid & 3) * 16;
    const float* src = qkvf + (long)(s0 + rr) * 3072 + 2560 + kvh * 128 + d0 + cs;
    for (int u = 0; u < 4; ++u) {
        float4 v = *(const float4*)(src + u * 4);
        t[rr][cs + u * 4 + 0] = v.x; t[rr][cs + u * 4 + 1] = v.y;
        t[rr][cs + u * 4 + 2] = v.z; t[rr][cs + u * 4 + 3] = v.w;
    }
    __syncthreads();
    int dr = tid >> 2, ss = (tid & 3) * 16;
    f16x8 h0, l0, h1, l1;
    for (int u = 0; u < 8; ++u)  { hl16 e = fsp(t[ss + u][dr]);     h0[u] = e.h; l0[u] = e.l; }
    for (int u = 0; u < 8; ++u)  { hl16 e = fsp(t[ss + 8 + u][dr]); h1[u] = e.h; l1[u] = e.l; }
    long ob = ((long)kvh * 128 + d0 + dr) * 2048 + s0 + ss;
    *(f16x8*)(vth + ob) = h0; *(f16x8*)(vth + ob + 8) = h1;
    *(f16x8*)(vtl + ob) = l0; *(f16x8*)(vtl + ob + 8) = l1;
}

// ---------------------------------------------------------------- flash attention, uniform 8-tile chunks
__global__ __launch_bounds__(256) void attn_k(
    const float* __restrict__ qkvf,
    const _Float16* __restrict__ kh, const _Float16* __restrict__ kl,
    const _Float16* __restrict__ vth, const _Float16* __restrict__ vtl,
    float* __restrict__ opart, float* __restrict__ mpart, float* __restrict__ lpart) {
    __shared__ __align__(16) _Float16 sKh[32][136], sKl[32][136];
    __shared__ __align__(16) _Float16 sVh[128][44], sVl[128][44];
    __shared__ __align__(16) _Float16 sPh[4][16][44], sPl[4][16][44];

    int bid = blockIdx.x, h = blockIdx.y, kvh = h >> 2;
    int qt = 0, cum = 0;
    for (int q = 0; q < 32; ++q) {
        int ch = (q >> 2) + 1;
        if (bid < cum + ch) { qt = q; break; }
        cum += ch;
    }
    int ci = bid - cum;
    int nt = 2 * (qt + 1);
    int t0 = ci * 8;
    int t1 = t0 + 8 < nt ? t0 + 8 : nt;
    int q0 = qt * 64;
    int tid = threadIdx.x, lane = tid & 63, wv = tid >> 6;
    int ln = lane & 15, g8 = (lane >> 4) * 8, rg = lane >> 4;

    f16x8 qh[4], ql[4];
    {
        int qrow = q0 + wv * 16 + ln;
        for (int ds = 0; ds < 4; ++ds) {
            const float* qp = qkvf + (long)qrow * 3072 + h * 128 + ds * 32 + g8;
            for (int j = 0; j < 8; ++j) { hl16 t = fsp(qp[j]); qh[ds][j] = t.h; ql[ds][j] = t.l; }
        }
    }

    f32x4 o[8];
    for (int i = 0; i < 8; ++i) o[i] = f32x4{0, 0, 0, 0};
    float mrow[4], lrow[4], al[4];
    for (int r = 0; r < 4; ++r) { mrow[r] = -3e38f; lrow[r] = 0.0f; }
    const float scale = 0.08838834764831845f;
    const float ILO = 1.0f / 2048.0f;

    int kr = tid >> 3, kc = (tid & 7) * 16;
    int vr = tid >> 1, vc = (tid & 1) * 16;

    for (int kt = t0; kt < t1; ++kt) {
        int kb = kt * 32;
        {
            long gb = ((long)kvh * 2048 + kb + kr) * 128 + kc;
            *(f16x8*)&sKh[kr][kc]     = *(const f16x8*)(kh + gb);
            *(f16x8*)&sKh[kr][kc + 8] = *(const f16x8*)(kh + gb + 8);
            *(f16x8*)&sKl[kr][kc]     = *(const f16x8*)(kl + gb);
            *(f16x8*)&sKl[kr][kc + 8] = *(const f16x8*)(kl + gb + 8);
        }
        {
            long gb = ((long)kvh * 128 + vr) * 2048 + kb + vc;
            *(f16x8*)&sVh[vr][vc]     = *(const f16x8*)(vth + gb);
            *(f16x8*)&sVh[vr][vc + 8] = *(const f16x8*)(vth + gb + 8);
            *(f16x8*)&sVl[vr][vc]     = *(const f16x8*)(vtl + gb);
            *(f16x8*)&sVl[vr][vc + 8] = *(const f16x8*)(vtl + gb + 8);
        }
        __syncthreads();

        f32x4 s1[2], s2[2];
        for (int j = 0; j < 2; ++j) { s1[j] = f32x4{0,0,0,0}; s2[j] = f32x4{0,0,0,0}; }
        for (int ds = 0; ds < 4; ++ds)
            for (int j = 0; j < 2; ++j) {
                int r = j * 16 + ln;
                f16x8 kfh = *(const f16x8*)&sKh[r][ds * 32 + g8];
                f16x8 kfl = *(const f16x8*)&sKl[r][ds * 32 + g8];
                s1[j] = __builtin_amdgcn_mfma_f32_16x16x32_f16(qh[ds], kfh, s1[j], 0, 0, 0);
                s2[j] = __builtin_amdgcn_mfma_f32_16x16x32_f16(ql[ds], kfh, s2[j], 0, 0, 0);
                s2[j] = __builtin_amdgcn_mfma_f32_16x16x32_f16(qh[ds], kfl, s2[j], 0, 0, 0);
            }

        float sv[2][4];
        bool dg = (kt >= 2 * qt);
        for (int j = 0; j < 2; ++j)
            for (int r = 0; r < 4; ++r) {
                float v = (s1[j][r] + s2[j][r] * ILO) * scale;
                if (dg) {
                    int col = kb + j * 16 + ln;
                    int rw = q0 + wv * 16 + rg * 4 + r;
                    if (col > rw) v = -1e9f;
                }
                sv[j][r] = v;
            }
        for (int r = 0; r < 4; ++r) {
            float mx = fmaxf(sv[0][r], sv[1][r]);
            for (int m = 1; m < 16; m <<= 1) mx = fmaxf(mx, __shfl_xor(mx, m));
            float mn = fmaxf(mrow[r], mx);
            al[r] = __expf(mrow[r] - mn);
            mrow[r] = mn;
            float rs = 0.0f;
            for (int j = 0; j < 2; ++j) {
                float p = __expf(sv[j][r] - mn);
                sv[j][r] = p;
                rs += p;
            }
            for (int m = 1; m < 16; m <<= 1) rs += __shfl_xor(rs, m);
            lrow[r] = lrow[r] * al[r] + rs;
        }
        for (int j = 0; j < 2; ++j)
            for (int r = 0; r < 4; ++r) {
                hl16 t = fsp(sv[j][r]);
                sPh[wv][rg * 4 + r][j * 16 + ln] = t.h;
                sPl[wv][rg * 4 + r][j * 16 + ln] = t.l;
            }
        for (int i = 0; i < 8; ++i)
            for (int r = 0; r < 4; ++r) o[i][r] *= al[r];
        f16x8 pah = *(const f16x8*)&sPh[wv][ln][g8];
        f16x8 pal = *(const f16x8*)&sPl[wv][ln][g8];
        f32x4 p2[8];
        for (int i = 0; i < 8; ++i) p2[i] = f32x4{0, 0, 0, 0};
        for (int i = 0; i < 8; ++i) {
            f16x8 vfh = *(const f16x8*)&sVh[i * 16 + ln][g8];
            f16x8 vfl = *(const f16x8*)&sVl[i * 16 + ln][g8];
            o[i]  = __builtin_amdgcn_mfma_f32_16x16x32_f16(pah, vfh, o[i], 0, 0, 0);
            p2[i] = __builtin_amdgcn_mfma_f32_16x16x32_f16(pal, vfh, p2[i], 0, 0, 0);
            p2[i] = __builtin_amdgcn_mfma_f32_16x16x32_f16(pah, vfl, p2[i], 0, 0, 0);
        }
        for (int i = 0; i < 8; ++i)
            for (int r = 0; r < 4; ++r) o[i][r] += p2[i][r] * ILO;
        __syncthreads();
    }

    long idx = (long)h * 144 + bid;
    float* ob = opart + idx * 8192;
    for (int r = 0; r < 4; ++r) {
        int rl = wv * 16 + rg * 4 + r;
        if (ln == 0) { mpart[idx * 64 + rl] = mrow[r]; lpart[idx * 64 + rl] = lrow[r]; }
        for (int i = 0; i < 8; ++i)
            ob[rl * 128 + i * 16 + ln] = o[i][r];
    }
}

// merge 1..8 chunks per (qt,h) — coalesced: lane owns 8 consecutive cols
__global__ __launch_bounds__(256) void merge_k(const float* __restrict__ opart,
                                               const float* __restrict__ mpart,
                                               const float* __restrict__ lpart,
                                               _Float16* __restrict__ ctxh,
                                               _Float16* __restrict__ ctxl) {
    int qt = blockIdx.x, h = blockIdx.y;
    int nch = (qt >> 2) + 1;
    int cum = 0;
    for (int q = 0; q < qt; ++q) cum += (q >> 2) + 1;
    long base = (long)h * 144 + cum;
    int tid = threadIdx.x;
    int cg = (tid & 15) * 8;
    for (int pass = 0; pass < 4; ++pass) {
        int row = pass * 16 + (tid >> 4);
        float mv[8], a[8];
        float M = -3e38f;
#pragma unroll
        for (int c = 0; c < 8; ++c) {
            mv[c] = (c < nch) ? mpart[(base + c) * 64 + row] : -3e38f;
            M = fmaxf(M, mv[c]);
        }
        float L = 0.f;
#pragma unroll
        for (int c = 0; c < 8; ++c) {
            a[c] = (c < nch) ? __expf(mv[c] - M) : 0.f;
            if (c < nch) L += lpart[(base + c) * 64 + row] * a[c];
        }
        float inv = 1.0f / L;
        float acc[8];
#pragma unroll
        for (int j = 0; j < 8; ++j) acc[j] = 0.f;
#pragma unroll
        for (int c = 0; c < 8; ++c) {
            if (c < nch) {
                const float* p = opart + (base + c) * 8192 + row * 128 + cg;
                float4 v0 = *(const float4*)(p);
                float4 v1 = *(const float4*)(p + 4);
                acc[0] += v0.x * a[c]; acc[1] += v0.y * a[c];
                acc[2] += v0.z * a[c]; acc[3] += v0.w * a[c];
                acc[4] += v1.x * a[c]; acc[5] += v1.y * a[c];
                acc[6] += v1.z * a[c]; acc[7] += v1.w * a[c];
            }
        }
        f16x8 oh, ol;
#pragma unroll
        for (int j = 0; j < 8; ++j) {
            hl16 t = fsp(acc[j] * inv);
            oh[j] = t.h; ol[j] = t.l;
        }
        long grow = (long)(qt * 64 + row) * 2048 + h * 128 + cg;
        *(f16x8*)(ctxh + grow) = oh;
        *(f16x8*)(ctxl + grow) = ol;
    }
}

// ---------------------------------------------------------------- router (fp32, from residual)
__global__ __launch_bounds__(256) void router_k(const float* __restrict__ res,
                                                const float* __restrict__ w2,
                                                const float* __restrict__ wg,
                                                int* __restrict__ ti, float* __restrict__ tw) {
    int t = blockIdx.x, tid = threadIdx.x;
    const float* xr = res + (long)t * 2048;
    float4 a = *(const float4*)(xr + tid * 8);
    float4 b = *(const float4*)(xr + tid * 8 + 4);
    float ss = a.x * a.x + a.y * a.y + a.z * a.z + a.w * a.w +
               b.x * b.x + b.y * b.y + b.z * b.z + b.w * b.w;
    for (int m = 1; m < 64; m <<= 1) ss += __shfl_xor(ss, m);
    __shared__ float red[4];
    __shared__ float lg[4][16];
    if ((tid & 63) == 0) red[tid >> 6] = ss;
    __syncthreads();
    float sc = rsqrtf((red[0] + red[1] + red[2] + red[3]) * (1.0f / 2048.0f) + 1e-6f);
    float part[16];
    for (int e = 0; e < 16; ++e) part[e] = 0.f;
    for (int k = tid; k < 2048; k += 256) {
        float xv = xr[k] * sc * w2[k];
        const float* wr = wg + k * 16;
        for (int e = 0; e < 16; ++e) part[e] += xv * wr[e];
    }
    for (int e = 0; e < 16; ++e)
        for (int m = 1; m < 64; m <<= 1) part[e] += __shfl_xor(part[e], m);
    if ((tid & 63) == 0)
        for (int e = 0; e < 16; ++e) lg[tid >> 6][e] = part[e];
    __syncthreads();
    if (tid == 0) {
        float logit[16];
        float mx = -3e38f;
        for (int e = 0; e < 16; ++e) {
            logit[e] = lg[0][e] + lg[1][e] + lg[2][e] + lg[3][e];
            mx = fmaxf(mx, logit[e]);
        }
        float sum = 0.f, pr[16];
        for (int e = 0; e < 16; ++e) { pr[e] = expf(logit[e] - mx); sum += pr[e]; }
        for (int e = 0; e < 16; ++e) pr[e] /= sum;
        int sel[4]; float sw[4]; float s4 = 0.f;
        unsigned used = 0;
        for (int j = 0; j < 4; ++j) {
            int be = 0; float bv = -1.f;
            for (int e = 0; e < 16; ++e)
                if (!((used >> e) & 1u) && pr[e] > bv) { bv = pr[e]; be = e; }
            used |= 1u << be; sel[j] = be; sw[j] = bv; s4 += bv;
        }
        for (int j = 0; j < 4; ++j) {
            ti[t * 4 + j] = sel[j];
            tw[t * 4 + j] = sw[j] / s4;
        }
    }
}

// ---------------------------------------------------------------- routing build
__global__ void build1_k(const int* __restrict__ ti, int* __restrict__ offs, int* __restrict__ curs) {
    __shared__ int c[16];
    int tid = threadIdx.x;
    if (tid < 16) c[tid] = 0;
    __syncthreads();
    for (int i = tid; i < 8192; i += 256) atomicAdd(&c[ti[i]], 1);
    __syncthreads();
    if (tid == 0) {
        int run = 0;
        for (int e = 0; e < 16; ++e) { offs[e] = run; curs[e] = run; run += c[e]; }
        offs[16] = run;
    }
}

__global__ void build2_k(const int* __restrict__ ti, const float* __restrict__ tw,
                         int* __restrict__ curs, int* __restrict__ perm, float* __restrict__ permw) {
    int i = blockIdx.x * 256 + threadIdx.x;
    if (i < 8192) {
        int e = ti[i];
        int pos = atomicAdd(&curs[e], 1);
        perm[pos] = i >> 2;
        permw[pos] = tw[i];
    }
}

// ---------------------------------------------------------------- launch
extern "C" void kernel_launch(void* const* d_in, const int* in_sizes, int n_in,
                              void* d_out, int out_size, void* d_ws, size_t ws_size,
                              hipStream_t stream) {
    const float* hidden    = (const float*)d_in[0];
    const int*   posids    = (const int*)d_in[1];
    const float* ln1       = (const float*)d_in[2];
    const float* ln2       = (const float*)d_in[3];
    const float* w_qkv     = (const float*)d_in[4];
    const float* w_o       = (const float*)d_in[5];
    const float* w_gate    = (const float*)d_in[6];
    const float* w_gu      = (const float*)d_in[7];
    const float* w_down    = (const float*)d_in[8];
    const float* w_sh_gu   = (const float*)d_in[9];
    const float* w_sh_down = (const float*)d_in[10];
    float* out = (float*)d_out;

    char* ws = (char*)d_ws;
    // ---- phase A (attention) ----
    _Float16* xh    = (_Float16*)(ws + 0);
    _Float16* xl    = (_Float16*)(ws + 8388608);
    float*    qkvf  = (float*)   (ws + 16777216);
    _Float16* kh    = (_Float16*)(ws + 41943040);
    _Float16* kl    = (_Float16*)(ws + 44040192);
    _Float16* vth   = (_Float16*)(ws + 46137344);
    _Float16* vtl   = (_Float16*)(ws + 48234496);
    _Float16* ctxh  = (_Float16*)(ws + 50331648);
    _Float16* ctxl  = (_Float16*)(ws + 58720256);
    _Float16* wTh   = (_Float16*)(ws + 67108864);
    _Float16* wTl   = (_Float16*)(ws + 79691776);
    _Float16* woTh  = (_Float16*)(ws + 67108864);
    _Float16* woTl  = (_Float16*)(ws + 75497472);
    float*    opart = (float*)   (ws + 92274688);
    float*    mpart = (float*)   (ws + 167772160);
    float*    lpart = (float*)   (ws + 168361984);
    float*    rtab  = (float*)   (ws + 168951808);
    // ---- phase B (MoE, overlays phase A) ----
    short*    x2b      = (short*)(ws + 0);           // 8MB
    short*    w_guT    = (short*)(ws + 8388608);     // 128MB, ends 142606336
    short*    act      = (short*)(ws + 142606336);   // 16MB, ends 159383552
    short*    w_downT  = (short*)(ws + 25165824);    // NOTE: overlays w_guT tail? NO — w_guT spans [8388608,142606336); keep w_downT after act
    short*    w_shguT  = (short*)(ws + 159383552);   // 8MB, ends 167772160
    short*    shact    = (short*)(ws + 167772160);   // 4MB, ends 171966464
    short*    w_shdownT= (short*)(ws + 171966464);   // 4MB, ends 176160768
    char*     rb       = ws + 176160768;
    int*   topk_idx = (int*)(rb);
    float* topk_w   = (float*)(rb + 32 * 1024);
    int*   perm     = (int*)(rb + 64 * 1024);
    float* permw    = (float*)(rb + 96 * 1024);
    int*   offs     = (int*)(rb + 128 * 1024);
    int*   curs     = (int*)(rb + 128 * 1024 + 256);
    short* w_downT2 = (short*)(rb + 160 * 1024);     // 64MB region after rb block
    // place w_downT safely after the small router block
    w_downT = w_downT2;

    // ---- attention path ----
    ropetab_k<<<2048, 64, 0, stream>>>(posids, rtab);
    rmsnorm_k<0><<<2048, 256, 0, stream>>>(hidden, ln1, xh, xl);
    tsplit_k<<<dim3(32, 48), 256, 0, stream>>>(w_qkv, 3072, wTh, wTl, 2048);
    pgemm_k<EPI_F32><<<dim3(48, 16), 256, 0, stream>>>(xh, xl, 2048, wTh, wTl, 2048,
                                                       qkvf, 3072, nullptr, 2048);
    ropeall_k<<<dim3(2048, 5), 256, 0, stream>>>(qkvf, rtab, kh, kl);
    vprep_k<<<dim3(32, 2, 4), 256, 0, stream>>>(qkvf, vth, vtl);
    attn_k<<<dim3(144, 16), 256, 0, stream>>>(qkvf, kh, kl, vth, vtl,
                                              opart, mpart, lpart);
    merge_k<<<dim3(32, 16), 256, 0, stream>>>(opart, mpart, lpart, ctxh, ctxl);
    tsplit_k<<<dim3(32, 32), 256, 0, stream>>>(w_o, 2048, woTh, woTl, 2048);
    pgemm_k<EPI_RESID><<<dim3(32, 16), 256, 0, stream>>>(ctxh, ctxl, 2048, woTh, woTl, 2048,
                                                         out, 2048, hidden, 2048);
    // ---- router ----
    rmsnorm_k<1><<<2048, 256, 0, stream>>>(out, ln2, x2b, nullptr);
    router_k<<<2048, 256, 0, stream>>>(out, ln2, w_gate, topk_idx, topk_w);
    build1_k<<<1, 256, 0, stream>>>(topk_idx, offs, curs);
    build2_k<<<32, 256, 0, stream>>>(topk_idx, topk_w, curs, perm, permw);
    // ---- routed experts: fused gu GEMM + SiLU -> act ----
    wprep_k<<<dim3(32, 32, 16), 256, 0, stream>>>(w_gu, w_guT, 2048, 2048);
    gugemm_k<true><<<dim3(16, 256), 256, 0, stream>>>(
        x2b, 2048, w_guT, 2048, (long)2048 * 2048, act, perm, offs, 2048);
    wprep_k<<<dim3(16, 32, 16), 256, 0, stream>>>(w_down, w_downT, 1024, 2048);
    bgemm_k<MEPI_ATOMIC, true><<<dim3(16, 256), 256, 0, stream>>>(
        act, 1024, w_downT, 1024, (long)1024 * 2048, out, 2048, perm, permw, offs, 1024, 0, 1);
    // ---- shared expert ----
    wprep_k<<<dim3(32, 32, 1), 256, 0, stream>>>(w_sh_gu, w_shguT, 2048, 2048);
    gugemm_k<false><<<dim3(16, 16), 256, 0, stream>>>(
        x2b, 2048, w_shguT, 2048, 0, shact, nullptr, nullptr, 2048);
    wprep_k<<<dim3(16, 32, 1), 256, 0, stream>>>(w_sh_down, w_shdownT, 1024, 2048);
    bgemm_k<MEPI_ATOMIC, false><<<dim3(16, 16), 256, 0, stream>>>(
        shact, 1024, w_shdownT, 1024, 0, out, 2048, perm, permw, offs, 1024, 0, 0);
}

// Round 13
// 826.473 us; speedup vs baseline: 1.0601x; 1.0601x over previous
//
#include <hip/hip_runtime.h>
#include <hip/hip_bf16.h>
#include <math.h>

#define DI __device__ __forceinline__

typedef __attribute__((ext_vector_type(8))) short bf16x8;
typedef __attribute__((ext_vector_type(4))) short bf16x4;
typedef __attribute__((ext_vector_type(8))) _Float16 f16x8;
typedef __attribute__((ext_vector_type(4))) _Float16 f16x4;
typedef __attribute__((ext_vector_type(4))) float f32x4;

DI float b2f(short s) {
    unsigned u = ((unsigned)(unsigned short)s) << 16;
    return __builtin_bit_cast(float, u);
}
DI short f2b(float f) {
    unsigned u = __builtin_bit_cast(unsigned, f);
    unsigned r = (u + 0x7fffu + ((u >> 16) & 1u)) >> 16;
    return (short)(unsigned short)r;
}
struct hl16 { _Float16 h, l; };
DI hl16 fsp(float f) {
    hl16 r;
    r.h = (_Float16)f;
    r.l = (_Float16)((f - (float)r.h) * 2048.0f);
    return r;
}

// ---------------------------------------------------------------- rmsnorm
template <int MODE>
__global__ __launch_bounds__(256) void rmsnorm_k(const float* __restrict__ x,
                                                 const float* __restrict__ w,
                                                 void* __restrict__ o1,
                                                 void* __restrict__ o2) {
    int row = blockIdx.x, tid = threadIdx.x;
    const float* xr = x + (long)row * 2048;
    float4 a = *(const float4*)(xr + tid * 8);
    float4 b = *(const float4*)(xr + tid * 8 + 4);
    float ss = a.x * a.x + a.y * a.y + a.z * a.z + a.w * a.w +
               b.x * b.x + b.y * b.y + b.z * b.z + b.w * b.w;
    for (int m = 1; m < 64; m <<= 1) ss += __shfl_xor(ss, m);
    __shared__ float red[4];
    if ((tid & 63) == 0) red[tid >> 6] = ss;
    __syncthreads();
    float sc = rsqrtf((red[0] + red[1] + red[2] + red[3]) * (1.0f / 2048.0f) + 1e-6f);
    float4 wa = *(const float4*)(w + tid * 8);
    float4 wb = *(const float4*)(w + tid * 8 + 4);
    float v[8] = {a.x * sc * wa.x, a.y * sc * wa.y, a.z * sc * wa.z, a.w * sc * wa.w,
                  b.x * sc * wb.x, b.y * sc * wb.y, b.z * sc * wb.z, b.w * sc * wb.w};
    if (MODE == 0) {
        f16x8 h, l;
        for (int j = 0; j < 8; ++j) { hl16 t = fsp(v[j]); h[j] = t.h; l[j] = t.l; }
        *(f16x8*)((_Float16*)o1 + (long)row * 2048 + tid * 8) = h;
        *(f16x8*)((_Float16*)o2 + (long)row * 2048 + tid * 8) = l;
    } else {
        bf16x8 o;
        for (int j = 0; j < 8; ++j) o[j] = f2b(v[j]);
        *(bf16x8*)((short*)o1 + (long)row * 2048 + tid * 8) = o;
    }
}

// ---------------------------------------------------------------- transpose + split: f32 [R][C] -> planes [C][R]
__global__ __launch_bounds__(256) void tsplit_k(const float* __restrict__ in, int ldin,
                                                _Float16* __restrict__ outh,
                                                _Float16* __restrict__ outl, int ldout) {
    __shared__ float t[64][68];
    int r0 = blockIdx.x * 64, c0 = blockIdx.y * 64;
    int tid = threadIdx.x;
    int rr = tid >> 2, cs = (tid & 3) * 16;
    const float* src = in + (long)(r0 + rr) * ldin + c0 + cs;
    for (int u = 0; u < 4; ++u) {
        float4 v = *(const float4*)(src + u * 4);
        t[rr][cs + u * 4 + 0] = v.x; t[rr][cs + u * 4 + 1] = v.y;
        t[rr][cs + u * 4 + 2] = v.z; t[rr][cs + u * 4 + 3] = v.w;
    }
    __syncthreads();
    int cr = tid >> 2, rs = (tid & 3) * 16;
    f16x8 h0, l0, h1, l1;
    for (int u = 0; u < 8; ++u)  { hl16 e = fsp(t[rs + u][cr]);     h0[u] = e.h; l0[u] = e.l; }
    for (int u = 0; u < 8; ++u)  { hl16 e = fsp(t[rs + 8 + u][cr]); h1[u] = e.h; l1[u] = e.l; }
    long ob = (long)(c0 + cr) * ldout + r0 + rs;
    *(f16x8*)(outh + ob) = h0; *(f16x8*)(outh + ob + 8) = h1;
    *(f16x8*)(outl + ob) = l0; *(f16x8*)(outl + ob + 8) = l1;
}

// ---------------------------------------------------------------- weight prep: f32 [E][R][C] -> bf16 [E][C][R]
__global__ __launch_bounds__(256) void wprep_k(const float* __restrict__ in,
                                               short* __restrict__ outp,
                                               int R, int C) {
    __shared__ float t[64][68];
    int r0 = blockIdx.x * 64, c0 = blockIdx.y * 64;
    long es = (long)R * C;
    in += blockIdx.z * es;
    outp += blockIdx.z * es;
    int tid = threadIdx.x;
    int rr = tid >> 2, cs = (tid & 3) * 16;
    const float* src = in + (long)(r0 + rr) * C + c0 + cs;
    for (int u = 0; u < 4; ++u) {
        float4 v = *(const float4*)(src + u * 4);
        t[rr][cs + u * 4 + 0] = v.x; t[rr][cs + u * 4 + 1] = v.y;
        t[rr][cs + u * 4 + 2] = v.z; t[rr][cs + u * 4 + 3] = v.w;
    }
    __syncthreads();
    int cr = tid >> 2, rs = (tid & 3) * 16;
    bf16x8 o0, o1;
    for (int u = 0; u < 8; ++u) o0[u] = f2b(t[rs + u][cr]);
    for (int u = 0; u < 8; ++u) o1[u] = f2b(t[rs + 8 + u][cr]);
    long ob = (long)(c0 + cr) * R + r0 + rs;
    *(bf16x8*)(outp + ob) = o0;
    *(bf16x8*)(outp + ob + 8) = o1;
}

// ---------------------------------------------------------------- precise GEMM on planes
// BM=128, BN=64, BK=64. 4 waves as 2Mx2N, wave tile 64x32.
enum { EPI_F32 = 0, EPI_RESID = 1 };

template <int EPI>
__global__ __launch_bounds__(256) void pgemm_k(
    const _Float16* __restrict__ Ah, const _Float16* __restrict__ Al, int lda,
    const _Float16* __restrict__ Bh, const _Float16* __restrict__ Bl, int ldb,
    float* __restrict__ C, int ldc,
    const float* __restrict__ resid, int K) {
    __shared__ __align__(16) _Float16 sAh[128][68], sAl[128][68];
    __shared__ __align__(16) _Float16 sBh[64][68], sBl[64][68];
    int n0 = blockIdx.x * 64, m0 = blockIdx.y * 128;
    int tid = threadIdx.x, lane = tid & 63, wv = tid >> 6;
    int wm = (wv >> 1) * 64, wn = (wv & 1) * 32;
    int ln = lane & 15, g8 = (lane >> 4) * 8, rg = lane >> 4;
    int tr = tid >> 3, tc = (tid & 7) * 8;

    f32x4 a1[4][2], a2[4][2];
    for (int i = 0; i < 4; ++i)
        for (int j = 0; j < 2; ++j) { a1[i][j] = f32x4{0,0,0,0}; a2[i][j] = f32x4{0,0,0,0}; }

    for (int k0 = 0; k0 < K; k0 += 64) {
        for (int s = 0; s < 4; ++s) {
            int r = tr + s * 32;
            long ga = (long)(m0 + r) * lda + k0 + tc;
            *(f16x8*)&sAh[r][tc] = *(const f16x8*)(Ah + ga);
            *(f16x8*)&sAl[r][tc] = *(const f16x8*)(Al + ga);
        }
        for (int s = 0; s < 2; ++s) {
            int r = tr + s * 32;
            long gb = (long)(n0 + r) * ldb + k0 + tc;
            *(f16x8*)&sBh[r][tc] = *(const f16x8*)(Bh + gb);
            *(f16x8*)&sBl[r][tc] = *(const f16x8*)(Bl + gb);
        }
        __syncthreads();
        for (int kk = 0; kk < 2; ++kk) {
            f16x8 ah[4], alo[4], bh[2], blo[2];
            for (int i = 0; i < 4; ++i) {
                int r = wm + i * 16 + ln;
                ah[i]  = *(const f16x8*)&sAh[r][kk * 32 + g8];
                alo[i] = *(const f16x8*)&sAl[r][kk * 32 + g8];
            }
            for (int j = 0; j < 2; ++j) {
                int r = wn + j * 16 + ln;
                bh[j]  = *(const f16x8*)&sBh[r][kk * 32 + g8];
                blo[j] = *(const f16x8*)&sBl[r][kk * 32 + g8];
            }
            for (int i = 0; i < 4; ++i)
                for (int j = 0; j < 2; ++j) {
                    a1[i][j] = __builtin_amdgcn_mfma_f32_16x16x32_f16(ah[i], bh[j], a1[i][j], 0, 0, 0);
                    a2[i][j] = __builtin_amdgcn_mfma_f32_16x16x32_f16(alo[i], bh[j], a2[i][j], 0, 0, 0);
                    a2[i][j] = __builtin_amdgcn_mfma_f32_16x16x32_f16(ah[i], blo[j], a2[i][j], 0, 0, 0);
                }
        }
        __syncthreads();
    }
    for (int i = 0; i < 4; ++i)
        for (int r = 0; r < 4; ++r) {
            int m = m0 + wm + i * 16 + rg * 4 + r;
            for (int j = 0; j < 2; ++j) {
                int col = n0 + wn + j * 16 + ln;
                float v = a1[i][j][r] + a2[i][j][r] * (1.0f / 2048.0f);
                if (EPI == EPI_RESID) v += resid[(long)m * ldc + col];
                C[(long)m * ldc + col] = v;
            }
        }
}

// ---------------------------------------------------------------- bf16 GEMM (down-proj path), reg-prefetch dbuf
enum { MEPI_BF16 = 0, MEPI_ATOMIC = 1 };

template <int EPI, bool EXPERT>
__global__ __launch_bounds__(256) void bgemm_k(
    const short* __restrict__ A, int lda,
    const short* __restrict__ Bt, int ldb, long bStride,
    void* __restrict__ C, int ldc,
    const int* __restrict__ perm, const float* __restrict__ permw,
    const int* __restrict__ offsets,
    int K, int gatherA, int gatherC) {
    __shared__ __align__(16) short sA[128][72], sB[128][72];

    int n0 = blockIdx.x * 128;
    int base = 0, cnt = 1 << 30, m0;
    if (EXPERT) {
        int e = blockIdx.y >> 4;
        m0 = (blockIdx.y & 15) * 128;
        base = offsets[e];
        cnt = offsets[e + 1] - base;
        if (m0 >= cnt) return;
        Bt += (long)e * bStride;
    } else {
        m0 = blockIdx.y * 128;
    }

    int tid = threadIdx.x, lane = tid & 63, wv = tid >> 6;
    int wm = (wv >> 1) * 64, wn = (wv & 1) * 64;
    int ln = lane & 15, g8 = (lane >> 4) * 8, rg = lane >> 4;
    int tr = tid >> 3, tc = (tid & 7) * 8;

    const short* aRow[4];
    const short* bRow[4];
    for (int s = 0; s < 4; ++s) {
        int m = m0 + tr + s * 32;
        if (EXPERT && m >= cnt) m = cnt - 1;
        int arow;
        if (EXPERT) arow = gatherA ? perm[base + m] : (base + m);
        else arow = m;
        aRow[s] = A + (long)arow * lda;
        bRow[s] = Bt + (long)(n0 + tr + s * 32) * ldb;
    }

    f32x4 acc[4][4];
    for (int i = 0; i < 4; ++i)
        for (int j = 0; j < 4; ++j) acc[i][j] = f32x4{0.f, 0.f, 0.f, 0.f};

    int nkt = K >> 6;
    bf16x8 pa[4], pb[4];
    for (int s = 0; s < 4; ++s) {
        pa[s] = *(const bf16x8*)(aRow[s] + tc);
        pb[s] = *(const bf16x8*)(bRow[s] + tc);
    }
    for (int kt = 0; kt < nkt; ++kt) {
        for (int s = 0; s < 4; ++s) {
            int r = tr + s * 32;
            *(bf16x8*)&sA[r][tc] = pa[s];
            *(bf16x8*)&sB[r][tc] = pb[s];
        }
        __syncthreads();
        if (kt + 1 < nkt) {
            int k1 = (kt + 1) << 6;
            for (int s = 0; s < 4; ++s) {
                pa[s] = *(const bf16x8*)(aRow[s] + k1 + tc);
                pb[s] = *(const bf16x8*)(bRow[s] + k1 + tc);
            }
        }
        for (int kk = 0; kk < 2; ++kk) {
            bf16x8 af[4], bfr[4];
            for (int i = 0; i < 4; ++i)
                af[i] = *(const bf16x8*)&sA[wm + i * 16 + ln][kk * 32 + g8];
            for (int j = 0; j < 4; ++j)
                bfr[j] = *(const bf16x8*)&sB[wn + j * 16 + ln][kk * 32 + g8];
            for (int i = 0; i < 4; ++i)
                for (int j = 0; j < 4; ++j)
                    acc[i][j] = __builtin_amdgcn_mfma_f32_16x16x32_bf16(af[i], bfr[j], acc[i][j], 0, 0, 0);
        }
        __syncthreads();
    }

    for (int i = 0; i < 4; ++i) {
        for (int r = 0; r < 4; ++r) {
            int m = m0 + wm + i * 16 + rg * 4 + r;
            if (EXPERT && m >= cnt) continue;
            int crow;
            if (EXPERT) crow = gatherC ? perm[base + m] : (base + m);
            else crow = m;
            float cs = 1.0f;
            if (EPI == MEPI_ATOMIC && EXPERT && gatherC) cs = permw[base + m];
            for (int j = 0; j < 4; ++j) {
                int col = n0 + wn + j * 16 + ln;
                float v = acc[i][j][r];
                if (EPI == MEPI_BF16)
                    ((short*)C)[(long)crow * ldc + col] = f2b(v);
                else
                    atomicAdd(&((float*)C)[(long)crow * ldc + col], v * cs);
            }
        }
    }
}

// ---------------------------------------------------------------- fused gate/up GEMM + SiLU, reg-prefetch dbuf
template <bool EXPERT>
__global__ __launch_bounds__(256) void gugemm_k(
    const short* __restrict__ A, int lda,
    const short* __restrict__ Bt, int ldb, long bStride,
    short* __restrict__ act,
    const int* __restrict__ perm, const int* __restrict__ offsets, int K) {
    __shared__ __align__(16) short sA[128][72], sB[128][72];

    int n0 = blockIdx.x * 64;
    int base = 0, cnt = 1 << 30, m0;
    if (EXPERT) {
        int e = blockIdx.y >> 4;
        m0 = (blockIdx.y & 15) * 128;
        base = offsets[e];
        cnt = offsets[e + 1] - base;
        if (m0 >= cnt) return;
        Bt += (long)e * bStride;
    } else {
        m0 = blockIdx.y * 128;
    }

    int tid = threadIdx.x, lane = tid & 63, wv = tid >> 6;
    int wm = (wv >> 1) * 64, wn = (wv & 1) * 32;
    int ln = lane & 15, g8 = (lane >> 4) * 8, rg = lane >> 4;
    int tr = tid >> 3, tc = (tid & 7) * 8;

    const short* aRow[4];
    const short* bRow[4];
    for (int s = 0; s < 4; ++s) {
        int m = m0 + tr + s * 32;
        if (EXPERT && m >= cnt) m = cnt - 1;
        int arow;
        if (EXPERT) arow = perm[base + m];
        else arow = m;
        aRow[s] = A + (long)arow * lda;
        int r = tr + s * 32;
        int gr = (r < 64) ? (n0 + r) : (1024 + n0 + r - 64);
        bRow[s] = Bt + (long)gr * ldb;
    }

    f32x4 accg[4][2], accu[4][2];
    for (int i = 0; i < 4; ++i)
        for (int j = 0; j < 2; ++j) { accg[i][j] = f32x4{0.f,0.f,0.f,0.f}; accu[i][j] = f32x4{0.f,0.f,0.f,0.f}; }

    int nkt = K >> 6;
    bf16x8 pa[4], pb[4];
    for (int s = 0; s < 4; ++s) {
        pa[s] = *(const bf16x8*)(aRow[s] + tc);
        pb[s] = *(const bf16x8*)(bRow[s] + tc);
    }
    for (int kt = 0; kt < nkt; ++kt) {
        for (int s = 0; s < 4; ++s) {
            int r = tr + s * 32;
            *(bf16x8*)&sA[r][tc] = pa[s];
            *(bf16x8*)&sB[r][tc] = pb[s];
        }
        __syncthreads();
        if (kt + 1 < nkt) {
            int k1 = (kt + 1) << 6;
            for (int s = 0; s < 4; ++s) {
                pa[s] = *(const bf16x8*)(aRow[s] + k1 + tc);
                pb[s] = *(const bf16x8*)(bRow[s] + k1 + tc);
            }
        }
        for (int kk = 0; kk < 2; ++kk) {
            bf16x8 af[4], bg[2], bu[2];
            for (int i = 0; i < 4; ++i)
                af[i] = *(const bf16x8*)&sA[wm + i * 16 + ln][kk * 32 + g8];
            for (int j = 0; j < 2; ++j) {
                bg[j] = *(const bf16x8*)&sB[wn + j * 16 + ln][kk * 32 + g8];
                bu[j] = *(const bf16x8*)&sB[64 + wn + j * 16 + ln][kk * 32 + g8];
            }
            for (int i = 0; i < 4; ++i)
                for (int j = 0; j < 2; ++j) {
                    accg[i][j] = __builtin_amdgcn_mfma_f32_16x16x32_bf16(af[i], bg[j], accg[i][j], 0, 0, 0);
                    accu[i][j] = __builtin_amdgcn_mfma_f32_16x16x32_bf16(af[i], bu[j], accu[i][j], 0, 0, 0);
                }
        }
        __syncthreads();
    }

    for (int i = 0; i < 4; ++i) {
        for (int r = 0; r < 4; ++r) {
            int m = m0 + wm + i * 16 + rg * 4 + r;
            if (EXPERT && m >= cnt) continue;
            int crow = EXPERT ? (base + m) : m;
            for (int j = 0; j < 2; ++j) {
                int col = n0 + wn + j * 16 + ln;
                // replicate old gu->silu chain bitwise: f2b, b2f, silu, f2b
                float gf = b2f(f2b(accg[i][j][r]));
                float uf = b2f(f2b(accu[i][j][r]));
                float s = gf / (1.0f + __expf(-gf));
                act[(long)crow * 1024 + col] = f2b(s * uf);
            }
        }
    }
}

// ---------------------------------------------------------------- rope table (f64 accurate)
__global__ __launch_bounds__(64) void ropetab_k(const int* __restrict__ pos,
                                                float* __restrict__ tab) {
    int s = blockIdx.x, d = threadIdx.x;
    double inv = pow(10000.0, -(double)d / 64.0);
    double fr = (double)pos[s] * inv;
    tab[s * 128 + d] = (float)cos(fr);
    tab[s * 128 + 64 + d] = (float)sin(fr);
}

// rope q in-place; rope k -> split planes
__global__ __launch_bounds__(256) void ropeall_k(float* __restrict__ qkvf,
                                                 const float* __restrict__ tab,
                                                 _Float16* __restrict__ kh,
                                                 _Float16* __restrict__ kl) {
    int s = blockIdx.x, sub = threadIdx.x >> 6, d = threadIdx.x & 63;
    int hh = blockIdx.y * 4 + sub;
    float c = tab[s * 128 + d], sn = tab[s * 128 + 64 + d];
    if (hh < 16) {
        float* row = qkvf + (long)s * 3072 + hh * 128;
        float x1 = row[d], x2 = row[d + 64];
        row[d] = x1 * c - x2 * sn;
        row[d + 64] = x1 * sn + x2 * c;
    } else {
        int kvh = hh - 16;
        const float* row = qkvf + (long)s * 3072 + 2048 + kvh * 128;
        float x1 = row[d], x2 = row[d + 64];
        float y1 = x1 * c - x2 * sn, y2 = x1 * sn + x2 * c;
        hl16 a = fsp(y1), b = fsp(y2);
        long base = ((long)kvh * 2048 + s) * 128;
        kh[base + d] = a.h; kl[base + d] = a.l;
        kh[base + 64 + d] = b.h; kl[base + 64 + d] = b.l;
    }
}

// V transpose + split: qkvf v-section -> vt planes [kvh][128][2048]
__global__ __launch_bounds__(256) void vprep_k(const float* __restrict__ qkvf,
                                               _Float16* __restrict__ vth,
                                               _Float16* __restrict__ vtl) {
    __shared__ float t[64][68];
    int s0 = blockIdx.x * 64, d0 = blockIdx.y * 64, kvh = blockIdx.z;
    int tid = threadIdx.x;
    int rr = tid >> 2, cs = (tid & 3) * 16;
    const float* src = qkvf + (long)(s0 + rr) * 3072 + 2560 + kvh * 128 + d0 + cs;
    for (int u = 0; u < 4; ++u) {
        float4 v = *(const float4*)(src + u * 4);
        t[rr][cs + u * 4 + 0] = v.x; t[rr][cs + u * 4 + 1] = v.y;
        t[rr][cs + u * 4 + 2] = v.z; t[rr][cs + u * 4 + 3] = v.w;
    }
    __syncthreads();
    int dr = tid >> 2, ss = (tid & 3) * 16;
    f16x8 h0, l0, h1, l1;
    for (int u = 0; u < 8; ++u)  { hl16 e = fsp(t[ss + u][dr]);     h0[u] = e.h; l0[u] = e.l; }
    for (int u = 0; u < 8; ++u)  { hl16 e = fsp(t[ss + 8 + u][dr]); h1[u] = e.h; l1[u] = e.l; }
    long ob = ((long)kvh * 128 + d0 + dr) * 2048 + s0 + ss;
    *(f16x8*)(vth + ob) = h0; *(f16x8*)(vth + ob + 8) = h1;
    *(f16x8*)(vtl + ob) = l0; *(f16x8*)(vtl + ob + 8) = l1;
}

// ---------------------------------------------------------------- flash attention, uniform 8-tile chunks
__global__ __launch_bounds__(256) void attn_k(
    const float* __restrict__ qkvf,
    const _Float16* __restrict__ kh, const _Float16* __restrict__ kl,
    const _Float16* __restrict__ vth, const _Float16* __restrict__ vtl,
    float* __restrict__ opart, float* __restrict__ mpart, float* __restrict__ lpart) {
    __shared__ __align__(16) _Float16 sKh[32][136], sKl[32][136];
    __shared__ __align__(16) _Float16 sVh[128][44], sVl[128][44];
    __shared__ __align__(16) _Float16 sPh[4][16][44], sPl[4][16][44];

    int bid = blockIdx.x, h = blockIdx.y, kvh = h >> 2;
    int qt = 0, cum = 0;
    for (int q = 0; q < 32; ++q) {
        int ch = (q >> 2) + 1;
        if (bid < cum + ch) { qt = q; break; }
        cum += ch;
    }
    int ci = bid - cum;
    int nt = 2 * (qt + 1);
    int t0 = ci * 8;
    int t1 = t0 + 8 < nt ? t0 + 8 : nt;
    int q0 = qt * 64;
    int tid = threadIdx.x, lane = tid & 63, wv = tid >> 6;
    int ln = lane & 15, g8 = (lane >> 4) * 8, rg = lane >> 4;

    f16x8 qh[4], ql[4];
    {
        int qrow = q0 + wv * 16 + ln;
        for (int ds = 0; ds < 4; ++ds) {
            const float* qp = qkvf + (long)qrow * 3072 + h * 128 + ds * 32 + g8;
            for (int j = 0; j < 8; ++j) { hl16 t = fsp(qp[j]); qh[ds][j] = t.h; ql[ds][j] = t.l; }
        }
    }

    f32x4 o[8];
    for (int i = 0; i < 8; ++i) o[i] = f32x4{0, 0, 0, 0};
    float mrow[4], lrow[4], al[4];
    for (int r = 0; r < 4; ++r) { mrow[r] = -3e38f; lrow[r] = 0.0f; }
    const float scale = 0.08838834764831845f;
    const float ILO = 1.0f / 2048.0f;

    int kr = tid >> 3, kc = (tid & 7) * 16;
    int vr = tid >> 1, vc = (tid & 1) * 16;

    for (int kt = t0; kt < t1; ++kt) {
        int kb = kt * 32;
        {
            long gb = ((long)kvh * 2048 + kb + kr) * 128 + kc;
            *(f16x8*)&sKh[kr][kc]     = *(const f16x8*)(kh + gb);
            *(f16x8*)&sKh[kr][kc + 8] = *(const f16x8*)(kh + gb + 8);
            *(f16x8*)&sKl[kr][kc]     = *(const f16x8*)(kl + gb);
            *(f16x8*)&sKl[kr][kc + 8] = *(const f16x8*)(kl + gb + 8);
        }
        {
            long gb = ((long)kvh * 128 + vr) * 2048 + kb + vc;
            *(f16x8*)&sVh[vr][vc]     = *(const f16x8*)(vth + gb);
            *(f16x8*)&sVh[vr][vc + 8] = *(const f16x8*)(vth + gb + 8);
            *(f16x8*)&sVl[vr][vc]     = *(const f16x8*)(vtl + gb);
            *(f16x8*)&sVl[vr][vc + 8] = *(const f16x8*)(vtl + gb + 8);
        }
        __syncthreads();

        f32x4 s1[2], s2[2];
        for (int j = 0; j < 2; ++j) { s1[j] = f32x4{0,0,0,0}; s2[j] = f32x4{0,0,0,0}; }
        for (int ds = 0; ds < 4; ++ds)
            for (int j = 0; j < 2; ++j) {
                int r = j * 16 + ln;
                f16x8 kfh = *(const f16x8*)&sKh[r][ds * 32 + g8];
                f16x8 kfl = *(const f16x8*)&sKl[r][ds * 32 + g8];
                s1[j] = __builtin_amdgcn_mfma_f32_16x16x32_f16(qh[ds], kfh, s1[j], 0, 0, 0);
                s2[j] = __builtin_amdgcn_mfma_f32_16x16x32_f16(ql[ds], kfh, s2[j], 0, 0, 0);
                s2[j] = __builtin_amdgcn_mfma_f32_16x16x32_f16(qh[ds], kfl, s2[j], 0, 0, 0);
            }

        float sv[2][4];
        bool dg = (kt >= 2 * qt);
        for (int j = 0; j < 2; ++j)
            for (int r = 0; r < 4; ++r) {
                float v = (s1[j][r] + s2[j][r] * ILO) * scale;
                if (dg) {
                    int col = kb + j * 16 + ln;
                    int rw = q0 + wv * 16 + rg * 4 + r;
                    if (col > rw) v = -1e9f;
                }
                sv[j][r] = v;
            }
        for (int r = 0; r < 4; ++r) {
            float mx = fmaxf(sv[0][r], sv[1][r]);
            for (int m = 1; m < 16; m <<= 1) mx = fmaxf(mx, __shfl_xor(mx, m));
            float mn = fmaxf(mrow[r], mx);
            al[r] = __expf(mrow[r] - mn);
            mrow[r] = mn;
            float rs = 0.0f;
            for (int j = 0; j < 2; ++j) {
                float p = __expf(sv[j][r] - mn);
                sv[j][r] = p;
                rs += p;
            }
            for (int m = 1; m < 16; m <<= 1) rs += __shfl_xor(rs, m);
            lrow[r] = lrow[r] * al[r] + rs;
        }
        for (int j = 0; j < 2; ++j)
            for (int r = 0; r < 4; ++r) {
                hl16 t = fsp(sv[j][r]);
                sPh[wv][rg * 4 + r][j * 16 + ln] = t.h;
                sPl[wv][rg * 4 + r][j * 16 + ln] = t.l;
            }
        for (int i = 0; i < 8; ++i)
            for (int r = 0; r < 4; ++r) o[i][r] *= al[r];
        f16x8 pah = *(const f16x8*)&sPh[wv][ln][g8];
        f16x8 pal = *(const f16x8*)&sPl[wv][ln][g8];
        f32x4 p2[8];
        for (int i = 0; i < 8; ++i) p2[i] = f32x4{0, 0, 0, 0};
        for (int i = 0; i < 8; ++i) {
            f16x8 vfh = *(const f16x8*)&sVh[i * 16 + ln][g8];
            f16x8 vfl = *(const f16x8*)&sVl[i * 16 + ln][g8];
            o[i]  = __builtin_amdgcn_mfma_f32_16x16x32_f16(pah, vfh, o[i], 0, 0, 0);
            p2[i] = __builtin_amdgcn_mfma_f32_16x16x32_f16(pal, vfh, p2[i], 0, 0, 0);
            p2[i] = __builtin_amdgcn_mfma_f32_16x16x32_f16(pah, vfl, p2[i], 0, 0, 0);
        }
        for (int i = 0; i < 8; ++i)
            for (int r = 0; r < 4; ++r) o[i][r] += p2[i][r] * ILO;
        __syncthreads();
    }

    long idx = (long)h * 144 + bid;
    float* ob = opart + idx * 8192;
    for (int r = 0; r < 4; ++r) {
        int rl = wv * 16 + rg * 4 + r;
        if (ln == 0) { mpart[idx * 64 + rl] = mrow[r]; lpart[idx * 64 + rl] = lrow[r]; }
        for (int i = 0; i < 8; ++i)
            ob[rl * 128 + i * 16 + ln] = o[i][r];
    }
}

// merge 1..8 chunks per (qt,h) — coalesced: lane owns 8 consecutive cols
__global__ __launch_bounds__(256) void merge_k(const float* __restrict__ opart,
                                               const float* __restrict__ mpart,
                                               const float* __restrict__ lpart,
                                               _Float16* __restrict__ ctxh,
                                               _Float16* __restrict__ ctxl) {
    int qt = blockIdx.x, h = blockIdx.y;
    int nch = (qt >> 2) + 1;
    int cum = 0;
    for (int q = 0; q < qt; ++q) cum += (q >> 2) + 1;
    long base = (long)h * 144 + cum;
    int tid = threadIdx.x;
    int cg = (tid & 15) * 8;
    for (int pass = 0; pass < 4; ++pass) {
        int row = pass * 16 + (tid >> 4);
        float mv[8], a[8];
        float M = -3e38f;
#pragma unroll
        for (int c = 0; c < 8; ++c) {
            mv[c] = (c < nch) ? mpart[(base + c) * 64 + row] : -3e38f;
            M = fmaxf(M, mv[c]);
        }
        float L = 0.f;
#pragma unroll
        for (int c = 0; c < 8; ++c) {
            a[c] = (c < nch) ? __expf(mv[c] - M) : 0.f;
            if (c < nch) L += lpart[(base + c) * 64 + row] * a[c];
        }
        float inv = 1.0f / L;
        float acc[8];
#pragma unroll
        for (int j = 0; j < 8; ++j) acc[j] = 0.f;
#pragma unroll
        for (int c = 0; c < 8; ++c) {
            if (c < nch) {
                const float* p = opart + (base + c) * 8192 + row * 128 + cg;
                float4 v0 = *(const float4*)(p);
                float4 v1 = *(const float4*)(p + 4);
                acc[0] += v0.x * a[c]; acc[1] += v0.y * a[c];
                acc[2] += v0.z * a[c]; acc[3] += v0.w * a[c];
                acc[4] += v1.x * a[c]; acc[5] += v1.y * a[c];
                acc[6] += v1.z * a[c]; acc[7] += v1.w * a[c];
            }
        }
        f16x8 oh, ol;
#pragma unroll
        for (int j = 0; j < 8; ++j) {
            hl16 t = fsp(acc[j] * inv);
            oh[j] = t.h; ol[j] = t.l;
        }
        long grow = (long)(qt * 64 + row) * 2048 + h * 128 + cg;
        *(f16x8*)(ctxh + grow) = oh;
        *(f16x8*)(ctxl + grow) = ol;
    }
}

// ---------------------------------------------------------------- router (fp32, from residual)
__global__ __launch_bounds__(256) void router_k(const float* __restrict__ res,
                                                const float* __restrict__ w2,
                                                const float* __restrict__ wg,
                                                int* __restrict__ ti, float* __restrict__ tw) {
    int t = blockIdx.x, tid = threadIdx.x;
    const float* xr = res + (long)t * 2048;
    float4 a = *(const float4*)(xr + tid * 8);
    float4 b = *(const float4*)(xr + tid * 8 + 4);
    float ss = a.x * a.x + a.y * a.y + a.z * a.z + a.w * a.w +
               b.x * b.x + b.y * b.y + b.z * b.z + b.w * b.w;
    for (int m = 1; m < 64; m <<= 1) ss += __shfl_xor(ss, m);
    __shared__ float red[4];
    __shared__ float lg[4][16];
    if ((tid & 63) == 0) red[tid >> 6] = ss;
    __syncthreads();
    float sc = rsqrtf((red[0] + red[1] + red[2] + red[3]) * (1.0f / 2048.0f) + 1e-6f);
    float part[16];
    for (int e = 0; e < 16; ++e) part[e] = 0.f;
    for (int k = tid; k < 2048; k += 256) {
        float xv = xr[k] * sc * w2[k];
        const float* wr = wg + k * 16;
        for (int e = 0; e < 16; ++e) part[e] += xv * wr[e];
    }
    for (int e = 0; e < 16; ++e)
        for (int m = 1; m < 64; m <<= 1) part[e] += __shfl_xor(part[e], m);
    if ((tid & 63) == 0)
        for (int e = 0; e < 16; ++e) lg[tid >> 6][e] = part[e];
    __syncthreads();
    if (tid == 0) {
        float logit[16];
        float mx = -3e38f;
        for (int e = 0; e < 16; ++e) {
            logit[e] = lg[0][e] + lg[1][e] + lg[2][e] + lg[3][e];
            mx = fmaxf(mx, logit[e]);
        }
        float sum = 0.f, pr[16];
        for (int e = 0; e < 16; ++e) { pr[e] = expf(logit[e] - mx); sum += pr[e]; }
        for (int e = 0; e < 16; ++e) pr[e] /= sum;
        int sel[4]; float sw[4]; float s4 = 0.f;
        unsigned used = 0;
        for (int j = 0; j < 4; ++j) {
            int be = 0; float bv = -1.f;
            for (int e = 0; e < 16; ++e)
                if (!((used >> e) & 1u) && pr[e] > bv) { bv = pr[e]; be = e; }
            used |= 1u << be; sel[j] = be; sw[j] = bv; s4 += bv;
        }
        for (int j = 0; j < 4; ++j) {
            ti[t * 4 + j] = sel[j];
            tw[t * 4 + j] = sw[j] / s4;
        }
    }
}

// ---------------------------------------------------------------- routing build
__global__ void build1_k(const int* __restrict__ ti, int* __restrict__ offs, int* __restrict__ curs) {
    __shared__ int c[16];
    int tid = threadIdx.x;
    if (tid < 16) c[tid] = 0;
    __syncthreads();
    for (int i = tid; i < 8192; i += 256) atomicAdd(&c[ti[i]], 1);
    __syncthreads();
    if (tid == 0) {
        int run = 0;
        for (int e = 0; e < 16; ++e) { offs[e] = run; curs[e] = run; run += c[e]; }
        offs[16] = run;
    }
}

__global__ void build2_k(const int* __restrict__ ti, const float* __restrict__ tw,
                         int* __restrict__ curs, int* __restrict__ perm, float* __restrict__ permw) {
    int i = blockIdx.x * 256 + threadIdx.x;
    if (i < 8192) {
        int e = ti[i];
        int pos = atomicAdd(&curs[e], 1);
        perm[pos] = i >> 2;
        permw[pos] = tw[i];
    }
}

// ---------------------------------------------------------------- launch
extern "C" void kernel_launch(void* const* d_in, const int* in_sizes, int n_in,
                              void* d_out, int out_size, void* d_ws, size_t ws_size,
                              hipStream_t stream) {
    const float* hidden    = (const float*)d_in[0];
    const int*   posids    = (const int*)d_in[1];
    const float* ln1       = (const float*)d_in[2];
    const float* ln2       = (const float*)d_in[3];
    const float* w_qkv     = (const float*)d_in[4];
    const float* w_o       = (const float*)d_in[5];
    const float* w_gate    = (const float*)d_in[6];
    const float* w_gu      = (const float*)d_in[7];
    const float* w_down    = (const float*)d_in[8];
    const float* w_sh_gu   = (const float*)d_in[9];
    const float* w_sh_down = (const float*)d_in[10];
    float* out = (float*)d_out;

    char* ws = (char*)d_ws;
    // ---- phase A (attention) ----
    _Float16* xh    = (_Float16*)(ws + 0);
    _Float16* xl    = (_Float16*)(ws + 8388608);
    float*    qkvf  = (float*)   (ws + 16777216);
    _Float16* kh    = (_Float16*)(ws + 41943040);
    _Float16* kl    = (_Float16*)(ws + 44040192);
    _Float16* vth   = (_Float16*)(ws + 46137344);
    _Float16* vtl   = (_Float16*)(ws + 48234496);
    _Float16* ctxh  = (_Float16*)(ws + 50331648);
    _Float16* ctxl  = (_Float16*)(ws + 58720256);
    _Float16* wTh   = (_Float16*)(ws + 67108864);
    _Float16* wTl   = (_Float16*)(ws + 79691776);
    _Float16* woTh  = (_Float16*)(ws + 67108864);
    _Float16* woTl  = (_Float16*)(ws + 75497472);
    float*    opart = (float*)   (ws + 92274688);
    float*    mpart = (float*)   (ws + 167772160);
    float*    lpart = (float*)   (ws + 168361984);
    float*    rtab  = (float*)   (ws + 168951808);
    // ---- phase B (MoE, overlays phase A) ----
    short*    x2b      = (short*)(ws + 0);           // 8MB
    short*    w_guT    = (short*)(ws + 8388608);     // 128MB, ends 142606336
    short*    act      = (short*)(ws + 142606336);   // 16MB, ends 159383552
    short*    w_shguT  = (short*)(ws + 159383552);   // 8MB, ends 167772160
    short*    shact    = (short*)(ws + 167772160);   // 4MB, ends 171966464
    short*    w_shdownT= (short*)(ws + 171966464);   // 4MB, ends 176160768
    char*     rb       = ws + 176160768;
    int*   topk_idx = (int*)(rb);
    float* topk_w   = (float*)(rb + 32 * 1024);
    int*   perm     = (int*)(rb + 64 * 1024);
    float* permw    = (float*)(rb + 96 * 1024);
    int*   offs     = (int*)(rb + 128 * 1024);
    int*   curs     = (int*)(rb + 128 * 1024 + 256);
    short* w_downT  = (short*)(rb + 160 * 1024);     // 64MB region after rb block

    // ---- attention path ----
    ropetab_k<<<2048, 64, 0, stream>>>(posids, rtab);
    rmsnorm_k<0><<<2048, 256, 0, stream>>>(hidden, ln1, xh, xl);
    tsplit_k<<<dim3(32, 48), 256, 0, stream>>>(w_qkv, 3072, wTh, wTl, 2048);
    pgemm_k<EPI_F32><<<dim3(48, 16), 256, 0, stream>>>(xh, xl, 2048, wTh, wTl, 2048,
                                                       qkvf, 3072, nullptr, 2048);
    ropeall_k<<<dim3(2048, 5), 256, 0, stream>>>(qkvf, rtab, kh, kl);
    vprep_k<<<dim3(32, 2, 4), 256, 0, stream>>>(qkvf, vth, vtl);
    attn_k<<<dim3(144, 16), 256, 0, stream>>>(qkvf, kh, kl, vth, vtl,
                                              opart, mpart, lpart);
    merge_k<<<dim3(32, 16), 256, 0, stream>>>(opart, mpart, lpart, ctxh, ctxl);
    tsplit_k<<<dim3(32, 32), 256, 0, stream>>>(w_o, 2048, woTh, woTl, 2048);
    pgemm_k<EPI_RESID><<<dim3(32, 16), 256, 0, stream>>>(ctxh, ctxl, 2048, woTh, woTl, 2048,
                                                         out, 2048, hidden, 2048);
    // ---- router ----
    rmsnorm_k<1><<<2048, 256, 0, stream>>>(out, ln2, x2b, nullptr);
    router_k<<<2048, 256, 0, stream>>>(out, ln2, w_gate, topk_idx, topk_w);
    build1_k<<<1, 256, 0, stream>>>(topk_idx, offs, curs);
    build2_k<<<32, 256, 0, stream>>>(topk_idx, topk_w, curs, perm, permw);
    // ---- routed experts: fused gu GEMM + SiLU -> act ----
    wprep_k<<<dim3(32, 32, 16), 256, 0, stream>>>(w_gu, w_guT, 2048, 2048);
    gugemm_k<true><<<dim3(16, 256), 256, 0, stream>>>(
        x2b, 2048, w_guT, 2048, (long)2048 * 2048, act, perm, offs, 2048);
    wprep_k<<<dim3(16, 32, 16), 256, 0, stream>>>(w_down, w_downT, 1024, 2048);
    bgemm_k<MEPI_ATOMIC, true><<<dim3(16, 256), 256, 0, stream>>>(
        act, 1024, w_downT, 1024, (long)1024 * 2048, out, 2048, perm, permw, offs, 1024, 0, 1);
    // ---- shared expert ----
    wprep_k<<<dim3(32, 32, 1), 256, 0, stream>>>(w_sh_gu, w_shguT, 2048, 2048);
    gugemm_k<false><<<dim3(16, 16), 256, 0, stream>>>(
        x2b, 2048, w_shguT, 2048, 0, shact, nullptr, nullptr, 2048);
    wprep_k<<<dim3(16, 32, 1), 256, 0, stream>>>(w_sh_down, w_shdownT, 1024, 2048);
    bgemm_k<MEPI_ATOMIC, false><<<dim3(16, 16), 256, 0, stream>>>(
        shact, 1024, w_shdownT, 1024, 0, out, 2048, perm, permw, offs, 1024, 0, 0);
}

// Round 14
// 825.184 us; speedup vs baseline: 1.0617x; 1.0016x over previous
//
#include <hip/hip_runtime.h>
#include <hip/hip_bf16.h>
#include <math.h>

#define DI __device__ __forceinline__

typedef __attribute__((ext_vector_type(8))) short bf16x8;
typedef __attribute__((ext_vector_type(4))) short bf16x4;
typedef __attribute__((ext_vector_type(8))) _Float16 f16x8;
typedef __attribute__((ext_vector_type(4))) _Float16 f16x4;
typedef __attribute__((ext_vector_type(4))) float f32x4;

DI float b2f(short s) {
    unsigned u = ((unsigned)(unsigned short)s) << 16;
    return __builtin_bit_cast(float, u);
}
DI short f2b(float f) {
    unsigned u = __builtin_bit_cast(unsigned, f);
    unsigned r = (u + 0x7fffu + ((u >> 16) & 1u)) >> 16;
    return (short)(unsigned short)r;
}
struct hl16 { _Float16 h, l; };
DI hl16 fsp(float f) {
    hl16 r;
    r.h = (_Float16)f;
    r.l = (_Float16)((f - (float)r.h) * 2048.0f);
    return r;
}

// ---------------------------------------------------------------- rmsnorm
template <int MODE>
__global__ __launch_bounds__(256) void rmsnorm_k(const float* __restrict__ x,
                                                 const float* __restrict__ w,
                                                 void* __restrict__ o1,
                                                 void* __restrict__ o2) {
    int row = blockIdx.x, tid = threadIdx.x;
    const float* xr = x + (long)row * 2048;
    float4 a = *(const float4*)(xr + tid * 8);
    float4 b = *(const float4*)(xr + tid * 8 + 4);
    float ss = a.x * a.x + a.y * a.y + a.z * a.z + a.w * a.w +
               b.x * b.x + b.y * b.y + b.z * b.z + b.w * b.w;
    for (int m = 1; m < 64; m <<= 1) ss += __shfl_xor(ss, m);
    __shared__ float red[4];
    if ((tid & 63) == 0) red[tid >> 6] = ss;
    __syncthreads();
    float sc = rsqrtf((red[0] + red[1] + red[2] + red[3]) * (1.0f / 2048.0f) + 1e-6f);
    float4 wa = *(const float4*)(w + tid * 8);
    float4 wb = *(const float4*)(w + tid * 8 + 4);
    float v[8] = {a.x * sc * wa.x, a.y * sc * wa.y, a.z * sc * wa.z, a.w * sc * wa.w,
                  b.x * sc * wb.x, b.y * sc * wb.y, b.z * sc * wb.z, b.w * sc * wb.w};
    if (MODE == 0) {
        f16x8 h, l;
        for (int j = 0; j < 8; ++j) { hl16 t = fsp(v[j]); h[j] = t.h; l[j] = t.l; }
        *(f16x8*)((_Float16*)o1 + (long)row * 2048 + tid * 8) = h;
        *(f16x8*)((_Float16*)o2 + (long)row * 2048 + tid * 8) = l;
    } else {
        bf16x8 o;
        for (int j = 0; j < 8; ++j) o[j] = f2b(v[j]);
        *(bf16x8*)((short*)o1 + (long)row * 2048 + tid * 8) = o;
    }
}

// ---------------------------------------------------------------- transpose + split: f32 [R][C] -> planes [C][R]
__global__ __launch_bounds__(256) void tsplit_k(const float* __restrict__ in, int ldin,
                                                _Float16* __restrict__ outh,
                                                _Float16* __restrict__ outl, int ldout) {
    __shared__ float t[64][68];
    int r0 = blockIdx.x * 64, c0 = blockIdx.y * 64;
    int tid = threadIdx.x;
    int rr = tid >> 2, cs = (tid & 3) * 16;
    const float* src = in + (long)(r0 + rr) * ldin + c0 + cs;
    for (int u = 0; u < 4; ++u) {
        float4 v = *(const float4*)(src + u * 4);
        t[rr][cs + u * 4 + 0] = v.x; t[rr][cs + u * 4 + 1] = v.y;
        t[rr][cs + u * 4 + 2] = v.z; t[rr][cs + u * 4 + 3] = v.w;
    }
    __syncthreads();
    int cr = tid >> 2, rs = (tid & 3) * 16;
    f16x8 h0, l0, h1, l1;
    for (int u = 0; u < 8; ++u)  { hl16 e = fsp(t[rs + u][cr]);     h0[u] = e.h; l0[u] = e.l; }
    for (int u = 0; u < 8; ++u)  { hl16 e = fsp(t[rs + 8 + u][cr]); h1[u] = e.h; l1[u] = e.l; }
    long ob = (long)(c0 + cr) * ldout + r0 + rs;
    *(f16x8*)(outh + ob) = h0; *(f16x8*)(outh + ob + 8) = h1;
    *(f16x8*)(outl + ob) = l0; *(f16x8*)(outl + ob + 8) = l1;
}

// ---------------------------------------------------------------- weight prep: f32 [E][R][C] -> bf16 [E][C][R]
__global__ __launch_bounds__(256) void wprep_k(const float* __restrict__ in,
                                               short* __restrict__ outp,
                                               int R, int C) {
    __shared__ float t[64][68];
    int r0 = blockIdx.x * 64, c0 = blockIdx.y * 64;
    long es = (long)R * C;
    in += blockIdx.z * es;
    outp += blockIdx.z * es;
    int tid = threadIdx.x;
    int rr = tid >> 2, cs = (tid & 3) * 16;
    const float* src = in + (long)(r0 + rr) * C + c0 + cs;
    for (int u = 0; u < 4; ++u) {
        float4 v = *(const float4*)(src + u * 4);
        t[rr][cs + u * 4 + 0] = v.x; t[rr][cs + u * 4 + 1] = v.y;
        t[rr][cs + u * 4 + 2] = v.z; t[rr][cs + u * 4 + 3] = v.w;
    }
    __syncthreads();
    int cr = tid >> 2, rs = (tid & 3) * 16;
    bf16x8 o0, o1;
    for (int u = 0; u < 8; ++u) o0[u] = f2b(t[rs + u][cr]);
    for (int u = 0; u < 8; ++u) o1[u] = f2b(t[rs + 8 + u][cr]);
    long ob = (long)(c0 + cr) * R + r0 + rs;
    *(bf16x8*)(outp + ob) = o0;
    *(bf16x8*)(outp + ob + 8) = o1;
}

// ---------------------------------------------------------------- precise GEMM on planes
// BM=128, BN=64, BK=64. 4 waves as 2Mx2N, wave tile 64x32.
enum { EPI_F32 = 0, EPI_RESID = 1 };

template <int EPI>
__global__ __launch_bounds__(256) void pgemm_k(
    const _Float16* __restrict__ Ah, const _Float16* __restrict__ Al, int lda,
    const _Float16* __restrict__ Bh, const _Float16* __restrict__ Bl, int ldb,
    float* __restrict__ C, int ldc,
    const float* __restrict__ resid, int K) {
    __shared__ __align__(16) _Float16 sAh[128][68], sAl[128][68];
    __shared__ __align__(16) _Float16 sBh[64][68], sBl[64][68];
    int n0 = blockIdx.x * 64, m0 = blockIdx.y * 128;
    int tid = threadIdx.x, lane = tid & 63, wv = tid >> 6;
    int wm = (wv >> 1) * 64, wn = (wv & 1) * 32;
    int ln = lane & 15, g8 = (lane >> 4) * 8, rg = lane >> 4;
    int tr = tid >> 3, tc = (tid & 7) * 8;

    f32x4 a1[4][2], a2[4][2];
    for (int i = 0; i < 4; ++i)
        for (int j = 0; j < 2; ++j) { a1[i][j] = f32x4{0,0,0,0}; a2[i][j] = f32x4{0,0,0,0}; }

    for (int k0 = 0; k0 < K; k0 += 64) {
        for (int s = 0; s < 4; ++s) {
            int r = tr + s * 32;
            long ga = (long)(m0 + r) * lda + k0 + tc;
            *(f16x8*)&sAh[r][tc] = *(const f16x8*)(Ah + ga);
            *(f16x8*)&sAl[r][tc] = *(const f16x8*)(Al + ga);
        }
        for (int s = 0; s < 2; ++s) {
            int r = tr + s * 32;
            long gb = (long)(n0 + r) * ldb + k0 + tc;
            *(f16x8*)&sBh[r][tc] = *(const f16x8*)(Bh + gb);
            *(f16x8*)&sBl[r][tc] = *(const f16x8*)(Bl + gb);
        }
        __syncthreads();
        for (int kk = 0; kk < 2; ++kk) {
            f16x8 ah[4], alo[4], bh[2], blo[2];
            for (int i = 0; i < 4; ++i) {
                int r = wm + i * 16 + ln;
                ah[i]  = *(const f16x8*)&sAh[r][kk * 32 + g8];
                alo[i] = *(const f16x8*)&sAl[r][kk * 32 + g8];
            }
            for (int j = 0; j < 2; ++j) {
                int r = wn + j * 16 + ln;
                bh[j]  = *(const f16x8*)&sBh[r][kk * 32 + g8];
                blo[j] = *(const f16x8*)&sBl[r][kk * 32 + g8];
            }
            for (int i = 0; i < 4; ++i)
                for (int j = 0; j < 2; ++j) {
                    a1[i][j] = __builtin_amdgcn_mfma_f32_16x16x32_f16(ah[i], bh[j], a1[i][j], 0, 0, 0);
                    a2[i][j] = __builtin_amdgcn_mfma_f32_16x16x32_f16(alo[i], bh[j], a2[i][j], 0, 0, 0);
                    a2[i][j] = __builtin_amdgcn_mfma_f32_16x16x32_f16(ah[i], blo[j], a2[i][j], 0, 0, 0);
                }
        }
        __syncthreads();
    }
    for (int i = 0; i < 4; ++i)
        for (int r = 0; r < 4; ++r) {
            int m = m0 + wm + i * 16 + rg * 4 + r;
            for (int j = 0; j < 2; ++j) {
                int col = n0 + wn + j * 16 + ln;
                float v = a1[i][j][r] + a2[i][j][r] * (1.0f / 2048.0f);
                if (EPI == EPI_RESID) v += resid[(long)m * ldc + col];
                C[(long)m * ldc + col] = v;
            }
        }
}

// ---------------------------------------------------------------- bf16 GEMM (down-proj path), reg-prefetch dbuf
enum { MEPI_BF16 = 0, MEPI_ATOMIC = 1 };

template <int EPI, bool EXPERT>
__global__ __launch_bounds__(256) void bgemm_k(
    const short* __restrict__ A, int lda,
    const short* __restrict__ Bt, int ldb, long bStride,
    void* __restrict__ C, int ldc,
    const int* __restrict__ perm, const float* __restrict__ permw,
    const int* __restrict__ offsets,
    int K, int gatherA, int gatherC) {
    __shared__ __align__(16) short sA[128][72], sB[128][72];

    int n0 = blockIdx.x * 128;
    int base = 0, cnt = 1 << 30, m0;
    if (EXPERT) {
        int e = blockIdx.y >> 4;
        m0 = (blockIdx.y & 15) * 128;
        base = offsets[e];
        cnt = offsets[e + 1] - base;
        if (m0 >= cnt) return;
        Bt += (long)e * bStride;
    } else {
        m0 = blockIdx.y * 128;
    }

    int tid = threadIdx.x, lane = tid & 63, wv = tid >> 6;
    int wm = (wv >> 1) * 64, wn = (wv & 1) * 64;
    int ln = lane & 15, g8 = (lane >> 4) * 8, rg = lane >> 4;
    int tr = tid >> 3, tc = (tid & 7) * 8;

    const short* aRow[4];
    const short* bRow[4];
    for (int s = 0; s < 4; ++s) {
        int m = m0 + tr + s * 32;
        if (EXPERT && m >= cnt) m = cnt - 1;
        int arow;
        if (EXPERT) arow = gatherA ? perm[base + m] : (base + m);
        else arow = m;
        aRow[s] = A + (long)arow * lda;
        bRow[s] = Bt + (long)(n0 + tr + s * 32) * ldb;
    }

    f32x4 acc[4][4];
    for (int i = 0; i < 4; ++i)
        for (int j = 0; j < 4; ++j) acc[i][j] = f32x4{0.f, 0.f, 0.f, 0.f};

    int nkt = K >> 6;
    bf16x8 pa[4], pb[4];
    for (int s = 0; s < 4; ++s) {
        pa[s] = *(const bf16x8*)(aRow[s] + tc);
        pb[s] = *(const bf16x8*)(bRow[s] + tc);
    }
    for (int kt = 0; kt < nkt; ++kt) {
        for (int s = 0; s < 4; ++s) {
            int r = tr + s * 32;
            *(bf16x8*)&sA[r][tc] = pa[s];
            *(bf16x8*)&sB[r][tc] = pb[s];
        }
        __syncthreads();
        if (kt + 1 < nkt) {
            int k1 = (kt + 1) << 6;
            for (int s = 0; s < 4; ++s) {
                pa[s] = *(const bf16x8*)(aRow[s] + k1 + tc);
                pb[s] = *(const bf16x8*)(bRow[s] + k1 + tc);
            }
        }
        for (int kk = 0; kk < 2; ++kk) {
            bf16x8 af[4], bfr[4];
            for (int i = 0; i < 4; ++i)
                af[i] = *(const bf16x8*)&sA[wm + i * 16 + ln][kk * 32 + g8];
            for (int j = 0; j < 4; ++j)
                bfr[j] = *(const bf16x8*)&sB[wn + j * 16 + ln][kk * 32 + g8];
            for (int i = 0; i < 4; ++i)
                for (int j = 0; j < 4; ++j)
                    acc[i][j] = __builtin_amdgcn_mfma_f32_16x16x32_bf16(af[i], bfr[j], acc[i][j], 0, 0, 0);
        }
        __syncthreads();
    }

    for (int i = 0; i < 4; ++i) {
        for (int r = 0; r < 4; ++r) {
            int m = m0 + wm + i * 16 + rg * 4 + r;
            if (EXPERT && m >= cnt) continue;
            int crow;
            if (EXPERT) crow = gatherC ? perm[base + m] : (base + m);
            else crow = m;
            float cs = 1.0f;
            if (EPI == MEPI_ATOMIC && EXPERT && gatherC) cs = permw[base + m];
            for (int j = 0; j < 4; ++j) {
                int col = n0 + wn + j * 16 + ln;
                float v = acc[i][j][r];
                if (EPI == MEPI_BF16)
                    ((short*)C)[(long)crow * ldc + col] = f2b(v);
                else
                    atomicAdd(&((float*)C)[(long)crow * ldc + col], v * cs);
            }
        }
    }
}

// ---------------------------------------------------------------- fused gate/up GEMM + SiLU, reg-prefetch dbuf
template <bool EXPERT>
__global__ __launch_bounds__(256) void gugemm_k(
    const short* __restrict__ A, int lda,
    const short* __restrict__ Bt, int ldb, long bStride,
    short* __restrict__ act,
    const int* __restrict__ perm, const int* __restrict__ offsets, int K) {
    __shared__ __align__(16) short sA[128][72], sB[128][72];

    int n0 = blockIdx.x * 64;
    int base = 0, cnt = 1 << 30, m0;
    if (EXPERT) {
        int e = blockIdx.y >> 4;
        m0 = (blockIdx.y & 15) * 128;
        base = offsets[e];
        cnt = offsets[e + 1] - base;
        if (m0 >= cnt) return;
        Bt += (long)e * bStride;
    } else {
        m0 = blockIdx.y * 128;
    }

    int tid = threadIdx.x, lane = tid & 63, wv = tid >> 6;
    int wm = (wv >> 1) * 64, wn = (wv & 1) * 32;
    int ln = lane & 15, g8 = (lane >> 4) * 8, rg = lane >> 4;
    int tr = tid >> 3, tc = (tid & 7) * 8;

    const short* aRow[4];
    const short* bRow[4];
    for (int s = 0; s < 4; ++s) {
        int m = m0 + tr + s * 32;
        if (EXPERT && m >= cnt) m = cnt - 1;
        int arow;
        if (EXPERT) arow = perm[base + m];
        else arow = m;
        aRow[s] = A + (long)arow * lda;
        int r = tr + s * 32;
        int gr = (r < 64) ? (n0 + r) : (1024 + n0 + r - 64);
        bRow[s] = Bt + (long)gr * ldb;
    }

    f32x4 accg[4][2], accu[4][2];
    for (int i = 0; i < 4; ++i)
        for (int j = 0; j < 2; ++j) { accg[i][j] = f32x4{0.f,0.f,0.f,0.f}; accu[i][j] = f32x4{0.f,0.f,0.f,0.f}; }

    int nkt = K >> 6;
    bf16x8 pa[4], pb[4];
    for (int s = 0; s < 4; ++s) {
        pa[s] = *(const bf16x8*)(aRow[s] + tc);
        pb[s] = *(const bf16x8*)(bRow[s] + tc);
    }
    for (int kt = 0; kt < nkt; ++kt) {
        for (int s = 0; s < 4; ++s) {
            int r = tr + s * 32;
            *(bf16x8*)&sA[r][tc] = pa[s];
            *(bf16x8*)&sB[r][tc] = pb[s];
        }
        __syncthreads();
        if (kt + 1 < nkt) {
            int k1 = (kt + 1) << 6;
            for (int s = 0; s < 4; ++s) {
                pa[s] = *(const bf16x8*)(aRow[s] + k1 + tc);
                pb[s] = *(const bf16x8*)(bRow[s] + k1 + tc);
            }
        }
        for (int kk = 0; kk < 2; ++kk) {
            bf16x8 af[4], bg[2], bu[2];
            for (int i = 0; i < 4; ++i)
                af[i] = *(const bf16x8*)&sA[wm + i * 16 + ln][kk * 32 + g8];
            for (int j = 0; j < 2; ++j) {
                bg[j] = *(const bf16x8*)&sB[wn + j * 16 + ln][kk * 32 + g8];
                bu[j] = *(const bf16x8*)&sB[64 + wn + j * 16 + ln][kk * 32 + g8];
            }
            for (int i = 0; i < 4; ++i)
                for (int j = 0; j < 2; ++j) {
                    accg[i][j] = __builtin_amdgcn_mfma_f32_16x16x32_bf16(af[i], bg[j], accg[i][j], 0, 0, 0);
                    accu[i][j] = __builtin_amdgcn_mfma_f32_16x16x32_bf16(af[i], bu[j], accu[i][j], 0, 0, 0);
                }
        }
        __syncthreads();
    }

    for (int i = 0; i < 4; ++i) {
        for (int r = 0; r < 4; ++r) {
            int m = m0 + wm + i * 16 + rg * 4 + r;
            if (EXPERT && m >= cnt) continue;
            int crow = EXPERT ? (base + m) : m;
            for (int j = 0; j < 2; ++j) {
                int col = n0 + wn + j * 16 + ln;
                // replicate old gu->silu chain bitwise: f2b, b2f, silu, f2b
                float gf = b2f(f2b(accg[i][j][r]));
                float uf = b2f(f2b(accu[i][j][r]));
                float s = gf / (1.0f + __expf(-gf));
                act[(long)crow * 1024 + col] = f2b(s * uf);
            }
        }
    }
}

// ---------------------------------------------------------------- rope table (f64 accurate)
__global__ __launch_bounds__(64) void ropetab_k(const int* __restrict__ pos,
                                                float* __restrict__ tab) {
    int s = blockIdx.x, d = threadIdx.x;
    double inv = pow(10000.0, -(double)d / 64.0);
    double fr = (double)pos[s] * inv;
    tab[s * 128 + d] = (float)cos(fr);
    tab[s * 128 + 64 + d] = (float)sin(fr);
}

// rope q in-place; rope k -> split planes
__global__ __launch_bounds__(256) void ropeall_k(float* __restrict__ qkvf,
                                                 const float* __restrict__ tab,
                                                 _Float16* __restrict__ kh,
                                                 _Float16* __restrict__ kl) {
    int s = blockIdx.x, sub = threadIdx.x >> 6, d = threadIdx.x & 63;
    int hh = blockIdx.y * 4 + sub;
    float c = tab[s * 128 + d], sn = tab[s * 128 + 64 + d];
    if (hh < 16) {
        float* row = qkvf + (long)s * 3072 + hh * 128;
        float x1 = row[d], x2 = row[d + 64];
        row[d] = x1 * c - x2 * sn;
        row[d + 64] = x1 * sn + x2 * c;
    } else {
        int kvh = hh - 16;
        const float* row = qkvf + (long)s * 3072 + 2048 + kvh * 128;
        float x1 = row[d], x2 = row[d + 64];
        float y1 = x1 * c - x2 * sn, y2 = x1 * sn + x2 * c;
        hl16 a = fsp(y1), b = fsp(y2);
        long base = ((long)kvh * 2048 + s) * 128;
        kh[base + d] = a.h; kl[base + d] = a.l;
        kh[base + 64 + d] = b.h; kl[base + 64 + d] = b.l;
    }
}

// V transpose + split: qkvf v-section -> vt planes [kvh][128][2048]
__global__ __launch_bounds__(256) void vprep_k(const float* __restrict__ qkvf,
                                               _Float16* __restrict__ vth,
                                               _Float16* __restrict__ vtl) {
    __shared__ float t[64][68];
    int s0 = blockIdx.x * 64, d0 = blockIdx.y * 64, kvh = blockIdx.z;
    int tid = threadIdx.x;
    int rr = tid >> 2, cs = (tid & 3) * 16;
    const float* src = qkvf + (long)(s0 + rr) * 3072 + 2560 + kvh * 128 + d0 + cs;
    for (int u = 0; u < 4; ++u) {
        float4 v = *(const float4*)(src + u * 4);
        t[rr][cs + u * 4 + 0] = v.x; t[rr][cs + u * 4 + 1] = v.y;
        t[rr][cs + u * 4 + 2] = v.z; t[rr][cs + u * 4 + 3] = v.w;
    }
    __syncthreads();
    int dr = tid >> 2, ss = (tid & 3) * 16;
    f16x8 h0, l0, h1, l1;
    for (int u = 0; u < 8; ++u)  { hl16 e = fsp(t[ss + u][dr]);     h0[u] = e.h; l0[u] = e.l; }
    for (int u = 0; u < 8; ++u)  { hl16 e = fsp(t[ss + 8 + u][dr]); h1[u] = e.h; l1[u] = e.l; }
    long ob = ((long)kvh * 128 + d0 + dr) * 2048 + s0 + ss;
    *(f16x8*)(vth + ob) = h0; *(f16x8*)(vth + ob + 8) = h1;
    *(f16x8*)(vtl + ob) = l0; *(f16x8*)(vtl + ob + 8) = l1;
}

// ---------------------------------------------------------------- flash attention, uniform 8-tile chunks
// reg-prefetch dbuf on K/V staging (LDS-bound at 2 blocks/CU, so +32 VGPR is free)
__global__ __launch_bounds__(256) void attn_k(
    const float* __restrict__ qkvf,
    const _Float16* __restrict__ kh, const _Float16* __restrict__ kl,
    const _Float16* __restrict__ vth, const _Float16* __restrict__ vtl,
    float* __restrict__ opart, float* __restrict__ mpart, float* __restrict__ lpart) {
    __shared__ __align__(16) _Float16 sKh[32][136], sKl[32][136];
    __shared__ __align__(16) _Float16 sVh[128][44], sVl[128][44];
    __shared__ __align__(16) _Float16 sPh[4][16][44], sPl[4][16][44];

    int bid = blockIdx.x, h = blockIdx.y, kvh = h >> 2;
    int qt = 0, cum = 0;
    for (int q = 0; q < 32; ++q) {
        int ch = (q >> 2) + 1;
        if (bid < cum + ch) { qt = q; break; }
        cum += ch;
    }
    int ci = bid - cum;
    int nt = 2 * (qt + 1);
    int t0 = ci * 8;
    int t1 = t0 + 8 < nt ? t0 + 8 : nt;
    int q0 = qt * 64;
    int tid = threadIdx.x, lane = tid & 63, wv = tid >> 6;
    int ln = lane & 15, g8 = (lane >> 4) * 8, rg = lane >> 4;

    f16x8 qh[4], ql[4];
    {
        int qrow = q0 + wv * 16 + ln;
        for (int ds = 0; ds < 4; ++ds) {
            const float* qp = qkvf + (long)qrow * 3072 + h * 128 + ds * 32 + g8;
            for (int j = 0; j < 8; ++j) { hl16 t = fsp(qp[j]); qh[ds][j] = t.h; ql[ds][j] = t.l; }
        }
    }

    f32x4 o[8];
    for (int i = 0; i < 8; ++i) o[i] = f32x4{0, 0, 0, 0};
    float mrow[4], lrow[4], al[4];
    for (int r = 0; r < 4; ++r) { mrow[r] = -3e38f; lrow[r] = 0.0f; }
    const float scale = 0.08838834764831845f;
    const float ILO = 1.0f / 2048.0f;

    int kr = tid >> 3, kc = (tid & 7) * 16;
    int vr = tid >> 1, vc = (tid & 1) * 16;

    // prefetch registers (8 x f16x8)
    f16x8 pk0, pk1, pk2, pk3, pv0, pv1, pv2, pv3;
    {
        int kb = t0 * 32;
        long gb = ((long)kvh * 2048 + kb + kr) * 128 + kc;
        pk0 = *(const f16x8*)(kh + gb);
        pk1 = *(const f16x8*)(kh + gb + 8);
        pk2 = *(const f16x8*)(kl + gb);
        pk3 = *(const f16x8*)(kl + gb + 8);
        long gv = ((long)kvh * 128 + vr) * 2048 + kb + vc;
        pv0 = *(const f16x8*)(vth + gv);
        pv1 = *(const f16x8*)(vth + gv + 8);
        pv2 = *(const f16x8*)(vtl + gv);
        pv3 = *(const f16x8*)(vtl + gv + 8);
    }

    for (int kt = t0; kt < t1; ++kt) {
        int kb = kt * 32;
        *(f16x8*)&sKh[kr][kc]     = pk0;
        *(f16x8*)&sKh[kr][kc + 8] = pk1;
        *(f16x8*)&sKl[kr][kc]     = pk2;
        *(f16x8*)&sKl[kr][kc + 8] = pk3;
        *(f16x8*)&sVh[vr][vc]     = pv0;
        *(f16x8*)&sVh[vr][vc + 8] = pv1;
        *(f16x8*)&sVl[vr][vc]     = pv2;
        *(f16x8*)&sVl[vr][vc + 8] = pv3;
        __syncthreads();
        if (kt + 1 < t1) {
            int kb1 = (kt + 1) * 32;
            long gb = ((long)kvh * 2048 + kb1 + kr) * 128 + kc;
            pk0 = *(const f16x8*)(kh + gb);
            pk1 = *(const f16x8*)(kh + gb + 8);
            pk2 = *(const f16x8*)(kl + gb);
            pk3 = *(const f16x8*)(kl + gb + 8);
            long gv = ((long)kvh * 128 + vr) * 2048 + kb1 + vc;
            pv0 = *(const f16x8*)(vth + gv);
            pv1 = *(const f16x8*)(vth + gv + 8);
            pv2 = *(const f16x8*)(vtl + gv);
            pv3 = *(const f16x8*)(vtl + gv + 8);
        }

        f32x4 s1[2], s2[2];
        for (int j = 0; j < 2; ++j) { s1[j] = f32x4{0,0,0,0}; s2[j] = f32x4{0,0,0,0}; }
        for (int ds = 0; ds < 4; ++ds)
            for (int j = 0; j < 2; ++j) {
                int r = j * 16 + ln;
                f16x8 kfh = *(const f16x8*)&sKh[r][ds * 32 + g8];
                f16x8 kfl = *(const f16x8*)&sKl[r][ds * 32 + g8];
                s1[j] = __builtin_amdgcn_mfma_f32_16x16x32_f16(qh[ds], kfh, s1[j], 0, 0, 0);
                s2[j] = __builtin_amdgcn_mfma_f32_16x16x32_f16(ql[ds], kfh, s2[j], 0, 0, 0);
                s2[j] = __builtin_amdgcn_mfma_f32_16x16x32_f16(qh[ds], kfl, s2[j], 0, 0, 0);
            }

        float sv[2][4];
        bool dg = (kt >= 2 * qt);
        for (int j = 0; j < 2; ++j)
            for (int r = 0; r < 4; ++r) {
                float v = (s1[j][r] + s2[j][r] * ILO) * scale;
                if (dg) {
                    int col = kb + j * 16 + ln;
                    int rw = q0 + wv * 16 + rg * 4 + r;
                    if (col > rw) v = -1e9f;
                }
                sv[j][r] = v;
            }
        for (int r = 0; r < 4; ++r) {
            float mx = fmaxf(sv[0][r], sv[1][r]);
            for (int m = 1; m < 16; m <<= 1) mx = fmaxf(mx, __shfl_xor(mx, m));
            float mn = fmaxf(mrow[r], mx);
            al[r] = __expf(mrow[r] - mn);
            mrow[r] = mn;
            float rs = 0.0f;
            for (int j = 0; j < 2; ++j) {
                float p = __expf(sv[j][r] - mn);
                sv[j][r] = p;
                rs += p;
            }
            for (int m = 1; m < 16; m <<= 1) rs += __shfl_xor(rs, m);
            lrow[r] = lrow[r] * al[r] + rs;
        }
        for (int j = 0; j < 2; ++j)
            for (int r = 0; r < 4; ++r) {
                hl16 t = fsp(sv[j][r]);
                sPh[wv][rg * 4 + r][j * 16 + ln] = t.h;
                sPl[wv][rg * 4 + r][j * 16 + ln] = t.l;
            }
        for (int i = 0; i < 8; ++i)
            for (int r = 0; r < 4; ++r) o[i][r] *= al[r];
        f16x8 pah = *(const f16x8*)&sPh[wv][ln][g8];
        f16x8 pal = *(const f16x8*)&sPl[wv][ln][g8];
        f32x4 p2[8];
        for (int i = 0; i < 8; ++i) p2[i] = f32x4{0, 0, 0, 0};
        for (int i = 0; i < 8; ++i) {
            f16x8 vfh = *(const f16x8*)&sVh[i * 16 + ln][g8];
            f16x8 vfl = *(const f16x8*)&sVl[i * 16 + ln][g8];
            o[i]  = __builtin_amdgcn_mfma_f32_16x16x32_f16(pah, vfh, o[i], 0, 0, 0);
            p2[i] = __builtin_amdgcn_mfma_f32_16x16x32_f16(pal, vfh, p2[i], 0, 0, 0);
            p2[i] = __builtin_amdgcn_mfma_f32_16x16x32_f16(pah, vfl, p2[i], 0, 0, 0);
        }
        for (int i = 0; i < 8; ++i)
            for (int r = 0; r < 4; ++r) o[i][r] += p2[i][r] * ILO;
        __syncthreads();
    }

    long idx = (long)h * 144 + bid;
    float* ob = opart + idx * 8192;
    for (int r = 0; r < 4; ++r) {
        int rl = wv * 16 + rg * 4 + r;
        if (ln == 0) { mpart[idx * 64 + rl] = mrow[r]; lpart[idx * 64 + rl] = lrow[r]; }
        for (int i = 0; i < 8; ++i)
            ob[rl * 128 + i * 16 + ln] = o[i][r];
    }
}

// merge 1..8 chunks per (qt,h) — coalesced: lane owns 8 consecutive cols
__global__ __launch_bounds__(256) void merge_k(const float* __restrict__ opart,
                                               const float* __restrict__ mpart,
                                               const float* __restrict__ lpart,
                                               _Float16* __restrict__ ctxh,
                                               _Float16* __restrict__ ctxl) {
    int qt = blockIdx.x, h = blockIdx.y;
    int nch = (qt >> 2) + 1;
    int cum = 0;
    for (int q = 0; q < qt; ++q) cum += (q >> 2) + 1;
    long base = (long)h * 144 + cum;
    int tid = threadIdx.x;
    int cg = (tid & 15) * 8;
    for (int pass = 0; pass < 4; ++pass) {
        int row = pass * 16 + (tid >> 4);
        float mv[8], a[8];
        float M = -3e38f;
#pragma unroll
        for (int c = 0; c < 8; ++c) {
            mv[c] = (c < nch) ? mpart[(base + c) * 64 + row] : -3e38f;
            M = fmaxf(M, mv[c]);
        }
        float L = 0.f;
#pragma unroll
        for (int c = 0; c < 8; ++c) {
            a[c] = (c < nch) ? __expf(mv[c] - M) : 0.f;
            if (c < nch) L += lpart[(base + c) * 64 + row] * a[c];
        }
        float inv = 1.0f / L;
        float acc[8];
#pragma unroll
        for (int j = 0; j < 8; ++j) acc[j] = 0.f;
#pragma unroll
        for (int c = 0; c < 8; ++c) {
            if (c < nch) {
                const float* p = opart + (base + c) * 8192 + row * 128 + cg;
                float4 v0 = *(const float4*)(p);
                float4 v1 = *(const float4*)(p + 4);
                acc[0] += v0.x * a[c]; acc[1] += v0.y * a[c];
                acc[2] += v0.z * a[c]; acc[3] += v0.w * a[c];
                acc[4] += v1.x * a[c]; acc[5] += v1.y * a[c];
                acc[6] += v1.z * a[c]; acc[7] += v1.w * a[c];
            }
        }
        f16x8 oh, ol;
#pragma unroll
        for (int j = 0; j < 8; ++j) {
            hl16 t = fsp(acc[j] * inv);
            oh[j] = t.h; ol[j] = t.l;
        }
        long grow = (long)(qt * 64 + row) * 2048 + h * 128 + cg;
        *(f16x8*)(ctxh + grow) = oh;
        *(f16x8*)(ctxl + grow) = ol;
    }
}

// ---------------------------------------------------------------- router (fp32, from residual)
__global__ __launch_bounds__(256) void router_k(const float* __restrict__ res,
                                                const float* __restrict__ w2,
                                                const float* __restrict__ wg,
                                                int* __restrict__ ti, float* __restrict__ tw) {
    int t = blockIdx.x, tid = threadIdx.x;
    const float* xr = res + (long)t * 2048;
    float4 a = *(const float4*)(xr + tid * 8);
    float4 b = *(const float4*)(xr + tid * 8 + 4);
    float ss = a.x * a.x + a.y * a.y + a.z * a.z + a.w * a.w +
               b.x * b.x + b.y * b.y + b.z * b.z + b.w * b.w;
    for (int m = 1; m < 64; m <<= 1) ss += __shfl_xor(ss, m);
    __shared__ float red[4];
    __shared__ float lg[4][16];
    if ((tid & 63) == 0) red[tid >> 6] = ss;
    __syncthreads();
    float sc = rsqrtf((red[0] + red[1] + red[2] + red[3]) * (1.0f / 2048.0f) + 1e-6f);
    float part[16];
    for (int e = 0; e < 16; ++e) part[e] = 0.f;
    for (int k = tid; k < 2048; k += 256) {
        float xv = xr[k] * sc * w2[k];
        const float* wr = wg + k * 16;
        for (int e = 0; e < 16; ++e) part[e] += xv * wr[e];
    }
    for (int e = 0; e < 16; ++e)
        for (int m = 1; m < 64; m <<= 1) part[e] += __shfl_xor(part[e], m);
    if ((tid & 63) == 0)
        for (int e = 0; e < 16; ++e) lg[tid >> 6][e] = part[e];
    __syncthreads();
    if (tid == 0) {
        float logit[16];
        float mx = -3e38f;
        for (int e = 0; e < 16; ++e) {
            logit[e] = lg[0][e] + lg[1][e] + lg[2][e] + lg[3][e];
            mx = fmaxf(mx, logit[e]);
        }
        float sum = 0.f, pr[16];
        for (int e = 0; e < 16; ++e) { pr[e] = expf(logit[e] - mx); sum += pr[e]; }
        for (int e = 0; e < 16; ++e) pr[e] /= sum;
        int sel[4]; float sw[4]; float s4 = 0.f;
        unsigned used = 0;
        for (int j = 0; j < 4; ++j) {
            int be = 0; float bv = -1.f;
            for (int e = 0; e < 16; ++e)
                if (!((used >> e) & 1u) && pr[e] > bv) { bv = pr[e]; be = e; }
            used |= 1u << be; sel[j] = be; sw[j] = bv; s4 += bv;
        }
        for (int j = 0; j < 4; ++j) {
            ti[t * 4 + j] = sel[j];
            tw[t * 4 + j] = sw[j] / s4;
        }
    }
}

// ---------------------------------------------------------------- routing build
__global__ void build1_k(const int* __restrict__ ti, int* __restrict__ offs, int* __restrict__ curs) {
    __shared__ int c[16];
    int tid = threadIdx.x;
    if (tid < 16) c[tid] = 0;
    __syncthreads();
    for (int i = tid; i < 8192; i += 256) atomicAdd(&c[ti[i]], 1);
    __syncthreads();
    if (tid == 0) {
        int run = 0;
        for (int e = 0; e < 16; ++e) { offs[e] = run; curs[e] = run; run += c[e]; }
        offs[16] = run;
    }
}

__global__ void build2_k(const int* __restrict__ ti, const float* __restrict__ tw,
                         int* __restrict__ curs, int* __restrict__ perm, float* __restrict__ permw) {
    int i = blockIdx.x * 256 + threadIdx.x;
    if (i < 8192) {
        int e = ti[i];
        int pos = atomicAdd(&curs[e], 1);
        perm[pos] = i >> 2;
        permw[pos] = tw[i];
    }
}

// ---------------------------------------------------------------- launch
extern "C" void kernel_launch(void* const* d_in, const int* in_sizes, int n_in,
                              void* d_out, int out_size, void* d_ws, size_t ws_size,
                              hipStream_t stream) {
    const float* hidden    = (const float*)d_in[0];
    const int*   posids    = (const int*)d_in[1];
    const float* ln1       = (const float*)d_in[2];
    const float* ln2       = (const float*)d_in[3];
    const float* w_qkv     = (const float*)d_in[4];
    const float* w_o       = (const float*)d_in[5];
    const float* w_gate    = (const float*)d_in[6];
    const float* w_gu      = (const float*)d_in[7];
    const float* w_down    = (const float*)d_in[8];
    const float* w_sh_gu   = (const float*)d_in[9];
    const float* w_sh_down = (const float*)d_in[10];
    float* out = (float*)d_out;

    char* ws = (char*)d_ws;
    // ---- phase A (attention) ----
    _Float16* xh    = (_Float16*)(ws + 0);
    _Float16* xl    = (_Float16*)(ws + 8388608);
    float*    qkvf  = (float*)   (ws + 16777216);
    _Float16* kh    = (_Float16*)(ws + 41943040);
    _Float16* kl    = (_Float16*)(ws + 44040192);
    _Float16* vth   = (_Float16*)(ws + 46137344);
    _Float16* vtl   = (_Float16*)(ws + 48234496);
    _Float16* ctxh  = (_Float16*)(ws + 50331648);
    _Float16* ctxl  = (_Float16*)(ws + 58720256);
    _Float16* wTh   = (_Float16*)(ws + 67108864);
    _Float16* wTl   = (_Float16*)(ws + 79691776);
    _Float16* woTh  = (_Float16*)(ws + 67108864);
    _Float16* woTl  = (_Float16*)(ws + 75497472);
    float*    opart = (float*)   (ws + 92274688);
    float*    mpart = (float*)   (ws + 167772160);
    float*    lpart = (float*)   (ws + 168361984);
    float*    rtab  = (float*)   (ws + 168951808);
    // ---- phase B (MoE, overlays phase A) ----
    short*    x2b      = (short*)(ws + 0);           // 8MB
    short*    w_guT    = (short*)(ws + 8388608);     // 128MB, ends 142606336
    short*    act      = (short*)(ws + 142606336);   // 16MB, ends 159383552
    short*    w_shguT  = (short*)(ws + 159383552);   // 8MB, ends 167772160
    short*    shact    = (short*)(ws + 167772160);   // 4MB, ends 171966464
    short*    w_shdownT= (short*)(ws + 171966464);   // 4MB, ends 176160768
    char*     rb       = ws + 176160768;
    int*   topk_idx = (int*)(rb);
    float* topk_w   = (float*)(rb + 32 * 1024);
    int*   perm     = (int*)(rb + 64 * 1024);
    float* permw    = (float*)(rb + 96 * 1024);
    int*   offs     = (int*)(rb + 128 * 1024);
    int*   curs     = (int*)(rb + 128 * 1024 + 256);
    short* w_downT  = (short*)(rb + 160 * 1024);     // 64MB region after rb block

    // ---- attention path ----
    ropetab_k<<<2048, 64, 0, stream>>>(posids, rtab);
    rmsnorm_k<0><<<2048, 256, 0, stream>>>(hidden, ln1, xh, xl);
    tsplit_k<<<dim3(32, 48), 256, 0, stream>>>(w_qkv, 3072, wTh, wTl, 2048);
    pgemm_k<EPI_F32><<<dim3(48, 16), 256, 0, stream>>>(xh, xl, 2048, wTh, wTl, 2048,
                                                       qkvf, 3072, nullptr, 2048);
    ropeall_k<<<dim3(2048, 5), 256, 0, stream>>>(qkvf, rtab, kh, kl);
    vprep_k<<<dim3(32, 2, 4), 256, 0, stream>>>(qkvf, vth, vtl);
    attn_k<<<dim3(144, 16), 256, 0, stream>>>(qkvf, kh, kl, vth, vtl,
                                              opart, mpart, lpart);
    merge_k<<<dim3(32, 16), 256, 0, stream>>>(opart, mpart, lpart, ctxh, ctxl);
    tsplit_k<<<dim3(32, 32), 256, 0, stream>>>(w_o, 2048, woTh, woTl, 2048);
    pgemm_k<EPI_RESID><<<dim3(32, 16), 256, 0, stream>>>(ctxh, ctxl, 2048, woTh, woTl, 2048,
                                                         out, 2048, hidden, 2048);
    // ---- router ----
    rmsnorm_k<1><<<2048, 256, 0, stream>>>(out, ln2, x2b, nullptr);
    router_k<<<2048, 256, 0, stream>>>(out, ln2, w_gate, topk_idx, topk_w);
    build1_k<<<1, 256, 0, stream>>>(topk_idx, offs, curs);
    build2_k<<<32, 256, 0, stream>>>(topk_idx, topk_w, curs, perm, permw);
    // ---- routed experts: fused gu GEMM + SiLU -> act ----
    wprep_k<<<dim3(32, 32, 16), 256, 0, stream>>>(w_gu, w_guT, 2048, 2048);
    gugemm_k<true><<<dim3(16, 256), 256, 0, stream>>>(
        x2b, 2048, w_guT, 2048, (long)2048 * 2048, act, perm, offs, 2048);
    wprep_k<<<dim3(16, 32, 16), 256, 0, stream>>>(w_down, w_downT, 1024, 2048);
    bgemm_k<MEPI_ATOMIC, true><<<dim3(16, 256), 256, 0, stream>>>(
        act, 1024, w_downT, 1024, (long)1024 * 2048, out, 2048, perm, permw, offs, 1024, 0, 1);
    // ---- shared expert ----
    wprep_k<<<dim3(32, 32, 1), 256, 0, stream>>>(w_sh_gu, w_shguT, 2048, 2048);
    gugemm_k<false><<<dim3(16, 16), 256, 0, stream>>>(
        x2b, 2048, w_shguT, 2048, 0, shact, nullptr, nullptr, 2048);
    wprep_k<<<dim3(16, 32, 1), 256, 0, stream>>>(w_sh_down, w_shdownT, 1024, 2048);
    bgemm_k<MEPI_ATOMIC, false><<<dim3(16, 16), 256, 0, stream>>>(
        shact, 1024, w_shdownT, 1024, 0, out, 2048, perm, permw, offs, 1024, 0, 0);
}